// Round 7
// baseline (816.778 us; speedup 1.0000x reference)
//
#include <hip/hip_runtime.h>
#include <hip/hip_bf16.h>
#include <math.h>

// Problem constants (from reference): D=64, L=2, R=4. N, E derived from sizes.
#define DD 64
#define RREL 4
#define LLAY 2
#define NEG_SLOPE 0.2f
#define EPB 4096   // edges per block in binning passes
#define BSH 10     // bucket shift: 1024 nodes per bucket
#define BSZ 1024

typedef __attribute__((ext_vector_type(8))) short short8;
typedef __attribute__((ext_vector_type(4))) short short4v;
typedef __attribute__((ext_vector_type(4))) float float4v;

__device__ __forceinline__ float lrelu(float x) { return x > 0.f ? x : NEG_SLOPE * x; }

// fp32 -> bf16 round-to-nearest-even (finite values)
__device__ __forceinline__ unsigned short f2bf(float f) {
    unsigned int u = __float_as_uint(f);
    return (unsigned short)((u + 0x7FFFu + ((u >> 16) & 1u)) >> 16);
}
__device__ __forceinline__ float bf2f(unsigned short u) {
    return __uint_as_float((unsigned int)u << 16);
}

// ---------- small precompute: wsrc/wdst = Wg @ a_src, Wg @ a_dst ----------
__global__ void k_wvec(const float* __restrict__ Wg, const float* __restrict__ asrc,
                       const float* __restrict__ adst, float* __restrict__ wsrc,
                       float* __restrict__ wdst) {
    int idx = blockIdx.x * blockDim.x + threadIdx.x;  // L*R*64 = 512
    if (idx >= LLAY * RREL * DD) return;
    int k = idx & 63;
    int lr = idx >> 6;
    const float* W = Wg + (size_t)lr * DD * DD;
    const float* as = asrc + lr * DD;
    const float* ad = adst + lr * DD;
    float s1 = 0.f, s2 = 0.f;
#pragma unroll
    for (int j = 0; j < DD; j++) {
        float w = W[k * DD + j];
        s1 += w * as[j];
        s2 += w * ad[j];
    }
    wsrc[idx] = s1;
    wdst[idx] = s2;
}

// ---------- weight prep: bf16, transposed [n][k]; W1 k-rows pi-permuted ----------
// pi(n) = (n&15)*4 + (n>>4)  (h-gemm packed-store column permutation)
// pi^-1(f) = (f&3)*16 + (f>>2)
__global__ void k_prep(const float* __restrict__ Wg, const float* __restrict__ W1,
                       const float* __restrict__ W2, unsigned short* __restrict__ WgT,
                       unsigned short* __restrict__ W1T, unsigned short* __restrict__ W2T) {
    int idx = blockIdx.x * blockDim.x + threadIdx.x;
    if (idx < 8 * 4096) {  // WgT[lr][n][k] = Wg[lr][k][n]  (k unpermuted: X side plain)
        int lr = idx >> 12, rem = idx & 4095, n = rem >> 6, k = rem & 63;
        WgT[idx] = f2bf(Wg[(size_t)lr * 4096 + k * 64 + n]);
    } else if (idx < 32768 + 2 * 64 * 320) {  // W1T[l][n][kk]
        int i = idx - 32768;
        int l = i / 20480, rem = i % 20480, n = rem / 320, kk = rem % 320;
        int src;
        if (kk < 64) src = kk;  // x-slice: unpermuted
        else {
            int r = (kk - 64) >> 6, f = (kk - 64) & 63;
            src = 64 + r * 64 + ((f & 3) * 16) + (f >> 2);  // h-slices: pi^-1
        }
        W1T[i] = f2bf(W1[(size_t)l * 20480 + src * 64 + n]);
    } else if (idx < 32768 + 40960 + 2 * 4096) {  // W2T[l][n][k] = W2[l][k][n]
        int i = idx - 73728;
        int l = i >> 12, rem = i & 4095, n = rem >> 6, k = rem & 63;
        W2T[i] = f2bf(W2[(size_t)l * 4096 + k * 64 + n]);
    }
}

// ---------- copy x into combined[:,0:64] (stride 320) ----------
__global__ void k_copy_x(const float* __restrict__ x, float* __restrict__ combined, int N) {
    int i = blockIdx.x * blockDim.x + threadIdx.x;  // N*16 float4s
    if (i >= N * 16) return;
    int row = i >> 4, c4 = i & 15;
    *(float4*)(combined + (size_t)row * 320 + c4 * 4) =
        *(const float4*)(x + (size_t)row * DD + c4 * 4);
}

// ---------- zero int buffer ----------
__global__ void k_zero(int* __restrict__ p, int n) {
    int i = blockIdx.x * blockDim.x + threadIdx.x;
    if (i < n) p[i] = 0;
}

// ---------- CSR pass A0: coarse bucket histogram (LDS-privatized) ----------
__global__ __launch_bounds__(256) void k_bhist(const int* __restrict__ edges,
                                               int* __restrict__ btot, int E, int NB) {
    int r = blockIdx.y;
    int e0 = blockIdx.x * EPB;
    int t = threadIdx.x;
    __shared__ int lh[128];
    for (int i = t; i < 128; i += 256) lh[i] = 0;
    __syncthreads();
    const int* dstp = edges + (size_t)r * 2 * E + E;
#pragma unroll
    for (int i = 0; i < EPB / 256; i++) {
        int e = e0 + t + 256 * i;
        if (e < E) atomicAdd(&lh[dstp[e] >> BSH], 1);
    }
    __syncthreads();
    for (int i = t; i < NB; i += 256) {
        int c = lh[i];
        if (c) atomicAdd(&btot[r * NB + i], c);
    }
}

// ---------- CSR pass A1: serial scan of bucket totals (tiny) ----------
__global__ void k_bscan(const int* __restrict__ btot, int* __restrict__ bucketoff,
                        int* __restrict__ bpos, int* __restrict__ csr_ptr, int N, int E, int NB) {
    int r = threadIdx.x;
    if (r >= RREL) return;
    int run = 0;
    for (int b = 0; b < NB; b++) {
        bucketoff[r * (NB + 1) + b] = run;
        bpos[r * NB + b] = run;
        run += btot[r * NB + b];
    }
    bucketoff[r * (NB + 1) + NB] = run;  // == E
    csr_ptr[(size_t)r * (N + 1) + N] = E;
}

// ---------- CSR pass A2: block-aggregated bin scatter (dense writes) ----------
__global__ __launch_bounds__(256) void k_binscatter(const int* __restrict__ edges,
                                                    int* __restrict__ bpos,
                                                    unsigned int* __restrict__ packed, int E,
                                                    int NB) {
    int r = blockIdx.y;
    int e0 = blockIdx.x * EPB;
    int t = threadIdx.x;
    __shared__ int lh[128], lbase[128];
    for (int i = t; i < 128; i += 256) lh[i] = 0;
    __syncthreads();
    const int* srcp = edges + (size_t)r * 2 * E;
    const int* dstp = srcp + E;
    int md[EPB / 256], ms[EPB / 256];
#pragma unroll
    for (int i = 0; i < EPB / 256; i++) {
        int e = e0 + t + 256 * i;
        int d = -1, s = 0;
        if (e < E) {
            d = dstp[e];
            s = srcp[e];
            atomicAdd(&lh[d >> BSH], 1);
        }
        md[i] = d;
        ms[i] = s;
    }
    __syncthreads();
    for (int i = t; i < NB; i += 256) {
        int c = lh[i];
        lbase[i] = c ? atomicAdd(&bpos[r * NB + i], c) : 0;
        lh[i] = 0;
    }
    __syncthreads();
#pragma unroll
    for (int i = 0; i < EPB / 256; i++) {
        if (md[i] >= 0) {
            int b = md[i] >> BSH;
            int p = lbase[b] + atomicAdd(&lh[b], 1);
            packed[(size_t)r * E + p] =
                ((unsigned int)(md[i] & (BSZ - 1)) << 17) | (unsigned int)ms[i];
        }
    }
}

// ---------- CSR pass B: per-bucket counting sort (L2-local) + csr_ptr ----------
__global__ __launch_bounds__(256) void k_bucket_sort(const unsigned int* __restrict__ packed,
                                                     const int* __restrict__ bucketoff,
                                                     int* __restrict__ csr_ptr,
                                                     int* __restrict__ csr_src, int N, int E,
                                                     int NB) {
    int r = blockIdx.y, b = blockIdx.x;
    int t = threadIdx.x;
    __shared__ int pos[BSZ];
    __shared__ int tsum[256];
    int base = bucketoff[r * (NB + 1) + b];
    int cnt = bucketoff[r * (NB + 1) + b + 1] - base;
    const unsigned int* pk = packed + (size_t)r * E + base;
    for (int i = t; i < BSZ; i += 256) pos[i] = 0;
    __syncthreads();
    for (int i = t; i < cnt; i += 256) atomicAdd(&pos[pk[i] >> 17], 1);
    __syncthreads();
    int v[4];
    int s = 0;
#pragma unroll
    for (int i = 0; i < 4; i++) {
        v[i] = pos[t * 4 + i];
        s += v[i];
    }
    tsum[t] = s;
    __syncthreads();
    for (int off = 1; off < 256; off <<= 1) {
        int add = (t >= off) ? tsum[t - off] : 0;
        __syncthreads();
        tsum[t] += add;
        __syncthreads();
    }
    int run = tsum[t] - s;  // exclusive
    __syncthreads();
#pragma unroll
    for (int i = 0; i < 4; i++) {
        int node_l = t * 4 + i;
        pos[node_l] = run;
        int node = b * BSZ + node_l;
        if (node < N) csr_ptr[(size_t)r * (N + 1) + node] = base + run;
        run += v[i];
    }
    __syncthreads();
    for (int i = t; i < cnt; i += 256) {
        unsigned int p = pk[i];
        int d = p >> 17;
        int sidx = p & 0x1FFFF;
        int loc = atomicAdd(&pos[d], 1);
        csr_src[(size_t)r * E + base + loc] = sidx;
    }
}

// ======== MFMA GEMM kernels: M-tile 256 (4 waves x 64 rows), N=64, 16x16x32 bf16 ========

// ---------- fused h-gemm: h_r = X@Wg_r (bf16, pi-packed), as/ad = X@wvec ----------
__global__ __launch_bounds__(256, 3) void k_hgemm(const float* __restrict__ X,
                                                  const unsigned short* __restrict__ WgTl,
                                                  const float* __restrict__ wsrcl,
                                                  const float* __restrict__ wdstl,
                                                  unsigned short* __restrict__ h4,
                                                  float* __restrict__ as4,
                                                  float* __restrict__ ad4, int N) {
    __shared__ __align__(16) unsigned short Xb[256][72];
    __shared__ __align__(16) unsigned short Wb[64][72];
    __shared__ float wsS[4][64], wdS[4][64];
    int tid = threadIdx.x, wave = tid >> 6, lane = tid & 63;
    int l15 = lane & 15, q = lane >> 4;
    int row0 = blockIdx.x * 256;
#pragma unroll
    for (int i = 0; i < 16; i++) {
        int f = tid + 256 * i;
        int rr = f >> 4, c4 = f & 15;
        int grow = row0 + rr;
        float4 v = make_float4(0.f, 0.f, 0.f, 0.f);
        if (grow < N) v = *(const float4*)(X + (size_t)grow * 320 + c4 * 4);
        short4v sv;
        sv[0] = (short)f2bf(v.x); sv[1] = (short)f2bf(v.y);
        sv[2] = (short)f2bf(v.z); sv[3] = (short)f2bf(v.w);
        *(short4v*)&Xb[rr][c4 * 4] = sv;
    }
    wsS[tid >> 6][tid & 63] = wsrcl[tid];
    wdS[tid >> 6][tid & 63] = wdstl[tid];
    __syncthreads();
    short8 afr[4][2];
#pragma unroll
    for (int mt = 0; mt < 4; mt++)
#pragma unroll
        for (int ks = 0; ks < 2; ks++)
            afr[mt][ks] = *(const short8*)&Xb[wave * 64 + mt * 16 + l15][ks * 32 + q * 8];
    {
        int grow = row0 + tid;
        float s[4] = {0.f, 0.f, 0.f, 0.f}, d[4] = {0.f, 0.f, 0.f, 0.f};
#pragma unroll
        for (int seg = 0; seg < 8; seg++) {
            short8 v = *(const short8*)&Xb[tid][seg * 8];
#pragma unroll
            for (int j = 0; j < 8; j++) {
                float xv = bf2f((unsigned short)v[j]);
                int k = seg * 8 + j;
#pragma unroll
                for (int r = 0; r < 4; r++) {
                    s[r] += xv * wsS[r][k];
                    d[r] += xv * wdS[r][k];
                }
            }
        }
        if (grow < N) {
#pragma unroll
            for (int r = 0; r < 4; r++) {
                as4[(size_t)r * N + grow] = s[r];
                ad4[(size_t)r * N + grow] = d[r];
            }
        }
    }
    for (int r = 0; r < 4; r++) {
        __syncthreads();
#pragma unroll
        for (int i = 0; i < 2; i++) {
            int f = tid + 256 * i;
            int n = f >> 3, seg = f & 7;
            *(short8*)&Wb[n][seg * 8] = *(const short8*)(WgTl + r * 4096 + n * 64 + seg * 8);
        }
        __syncthreads();
        short8 bfr[4][2];
#pragma unroll
        for (int nt = 0; nt < 4; nt++)
#pragma unroll
            for (int ks = 0; ks < 2; ks++)
                bfr[nt][ks] = *(const short8*)&Wb[nt * 16 + l15][ks * 32 + q * 8];
        float4v acc[4][4];
#pragma unroll
        for (int mt = 0; mt < 4; mt++)
#pragma unroll
            for (int nt = 0; nt < 4; nt++) acc[mt][nt] = (float4v){0.f, 0.f, 0.f, 0.f};
#pragma unroll
        for (int mt = 0; mt < 4; mt++)
#pragma unroll
            for (int nt = 0; nt < 4; nt++) {
                acc[mt][nt] = __builtin_amdgcn_mfma_f32_16x16x32_bf16(afr[mt][0], bfr[nt][0],
                                                                     acc[mt][nt], 0, 0, 0);
                acc[mt][nt] = __builtin_amdgcn_mfma_f32_16x16x32_bf16(afr[mt][1], bfr[nt][1],
                                                                     acc[mt][nt], 0, 0, 0);
            }
        unsigned short* hr = h4 + (size_t)r * N * 64;
#pragma unroll
        for (int mt = 0; mt < 4; mt++) {
            int rowb = row0 + wave * 64 + mt * 16 + q * 4;
#pragma unroll
            for (int reg = 0; reg < 4; reg++) {
                int row = rowb + reg;
                if (row < N) {
                    short4v sv;
                    sv[0] = (short)f2bf(acc[mt][0][reg]);
                    sv[1] = (short)f2bf(acc[mt][1][reg]);
                    sv[2] = (short)f2bf(acc[mt][2][reg]);
                    sv[3] = (short)f2bf(acc[mt][3][reg]);
                    *(short4v*)&hr[(size_t)row * 64 + l15 * 4] = sv;
                }
            }
        }
    }
}

// ---------- W1 gemm: hid = tanh(combined[N,320] @ W1 + b1), bf16 out ----------
__global__ __launch_bounds__(256, 3) void k_w1gemm(const float* __restrict__ X,
                                                   const unsigned short* __restrict__ WT,
                                                   const float* __restrict__ bias,
                                                   unsigned short* __restrict__ Y, int N) {
    __shared__ __align__(16) unsigned short Xb[256][72];
    __shared__ __align__(16) unsigned short Wb[64][72];
    int tid = threadIdx.x, wave = tid >> 6, lane = tid & 63;
    int l15 = lane & 15, q = lane >> 4;
    int row0 = blockIdx.x * 256;
    float4v acc[4][4];
#pragma unroll
    for (int mt = 0; mt < 4; mt++)
#pragma unroll
        for (int nt = 0; nt < 4; nt++) acc[mt][nt] = (float4v){0.f, 0.f, 0.f, 0.f};
    for (int kc = 0; kc < 320; kc += 64) {
        __syncthreads();
#pragma unroll
        for (int i = 0; i < 16; i++) {
            int f = tid + 256 * i;
            int rr = f >> 4, c4 = f & 15;
            int grow = row0 + rr;
            float4 v = make_float4(0.f, 0.f, 0.f, 0.f);
            if (grow < N) v = *(const float4*)(X + (size_t)grow * 320 + kc + c4 * 4);
            short4v sv;
            sv[0] = (short)f2bf(v.x); sv[1] = (short)f2bf(v.y);
            sv[2] = (short)f2bf(v.z); sv[3] = (short)f2bf(v.w);
            *(short4v*)&Xb[rr][c4 * 4] = sv;
        }
#pragma unroll
        for (int i = 0; i < 2; i++) {
            int f = tid + 256 * i;
            int n = f >> 3, seg = f & 7;
            *(short8*)&Wb[n][seg * 8] = *(const short8*)(WT + n * 320 + kc + seg * 8);
        }
        __syncthreads();
        short8 bfr[4][2];
#pragma unroll
        for (int nt = 0; nt < 4; nt++)
#pragma unroll
            for (int ks = 0; ks < 2; ks++)
                bfr[nt][ks] = *(const short8*)&Wb[nt * 16 + l15][ks * 32 + q * 8];
#pragma unroll
        for (int mt = 0; mt < 4; mt++) {
            short8 a0 = *(const short8*)&Xb[wave * 64 + mt * 16 + l15][q * 8];
            short8 a1 = *(const short8*)&Xb[wave * 64 + mt * 16 + l15][32 + q * 8];
#pragma unroll
            for (int nt = 0; nt < 4; nt++) {
                acc[mt][nt] =
                    __builtin_amdgcn_mfma_f32_16x16x32_bf16(a0, bfr[nt][0], acc[mt][nt], 0, 0, 0);
                acc[mt][nt] =
                    __builtin_amdgcn_mfma_f32_16x16x32_bf16(a1, bfr[nt][1], acc[mt][nt], 0, 0, 0);
            }
        }
    }
#pragma unroll
    for (int mt = 0; mt < 4; mt++) {
        int rowb = row0 + wave * 64 + mt * 16 + q * 4;
#pragma unroll
        for (int reg = 0; reg < 4; reg++) {
            int row = rowb + reg;
            if (row < N) {
#pragma unroll
                for (int nt = 0; nt < 4; nt++) {
                    int n = nt * 16 + l15;
                    float v = tanhf(acc[mt][nt][reg] + bias[n]);
                    Y[(size_t)row * 64 + n] = f2bf(v);
                }
            }
        }
    }
}

// ---------- W2 gemm: dest = hid[N,64](bf16) @ W2 + b2, fp32 out (ld param) ----------
__global__ __launch_bounds__(256, 3) void k_w2gemm(const unsigned short* __restrict__ X,
                                                   const unsigned short* __restrict__ WT,
                                                   const float* __restrict__ bias,
                                                   float* __restrict__ Y, int ldy, int N) {
    __shared__ __align__(16) unsigned short Xb[256][72];
    __shared__ __align__(16) unsigned short Wb[64][72];
    int tid = threadIdx.x, wave = tid >> 6, lane = tid & 63;
    int l15 = lane & 15, q = lane >> 4;
    int row0 = blockIdx.x * 256;
#pragma unroll
    for (int i = 0; i < 8; i++) {
        int f = tid + 256 * i;
        int rr = f >> 3, seg = f & 7;
        int grow = row0 + rr;
        short8 v = (short8){0, 0, 0, 0, 0, 0, 0, 0};
        if (grow < N) v = *(const short8*)(X + (size_t)grow * 64 + seg * 8);
        *(short8*)&Xb[rr][seg * 8] = v;
    }
#pragma unroll
    for (int i = 0; i < 2; i++) {
        int f = tid + 256 * i;
        int n = f >> 3, seg = f & 7;
        *(short8*)&Wb[n][seg * 8] = *(const short8*)(WT + n * 64 + seg * 8);
    }
    __syncthreads();
    short8 bfr[4][2];
#pragma unroll
    for (int nt = 0; nt < 4; nt++)
#pragma unroll
        for (int ks = 0; ks < 2; ks++)
            bfr[nt][ks] = *(const short8*)&Wb[nt * 16 + l15][ks * 32 + q * 8];
    float4v acc[4][4];
#pragma unroll
    for (int mt = 0; mt < 4; mt++)
#pragma unroll
        for (int nt = 0; nt < 4; nt++) acc[mt][nt] = (float4v){0.f, 0.f, 0.f, 0.f};
#pragma unroll
    for (int mt = 0; mt < 4; mt++) {
        short8 a0 = *(const short8*)&Xb[wave * 64 + mt * 16 + l15][q * 8];
        short8 a1 = *(const short8*)&Xb[wave * 64 + mt * 16 + l15][32 + q * 8];
#pragma unroll
        for (int nt = 0; nt < 4; nt++) {
            acc[mt][nt] =
                __builtin_amdgcn_mfma_f32_16x16x32_bf16(a0, bfr[nt][0], acc[mt][nt], 0, 0, 0);
            acc[mt][nt] =
                __builtin_amdgcn_mfma_f32_16x16x32_bf16(a1, bfr[nt][1], acc[mt][nt], 0, 0, 0);
        }
    }
#pragma unroll
    for (int mt = 0; mt < 4; mt++) {
        int rowb = row0 + wave * 64 + mt * 16 + q * 4;
#pragma unroll
        for (int reg = 0; reg < 4; reg++) {
            int row = rowb + reg;
            if (row < N) {
#pragma unroll
                for (int nt = 0; nt < 4; nt++) {
                    int n = nt * 16 + l15;
                    Y[(size_t)row * ldy + n] = acc[mt][nt][reg] + bias[n];
                }
            }
        }
    }
}

// ---------- full-wave per-node GAT (R6-proven path; used as rare fallback) ----------
__device__ void gat_node_fullwave(int node, const int* __restrict__ csr_ptr,
                                  const int* __restrict__ csr_src,
                                  const unsigned short* __restrict__ h,
                                  const float* __restrict__ as_,
                                  const float* __restrict__ ad_, float bgv,
                                  float* __restrict__ out, int ldo, int lane) {
    float adv = ad_[node];
    float e_self = lrelu(as_[node] + adv);
    int beg = csr_ptr[node], end = csr_ptr[node + 1];
    int cnt = end - beg;

    if (cnt <= 64) {
        int s = 0;
        float e_lane = -3.0e38f;
        if (lane < cnt) {
            s = csr_src[beg + lane];
            e_lane = lrelu(as_[s] + adv);
        }
        float m = fmaxf(e_lane, e_self);
#pragma unroll
        for (int off = 32; off; off >>= 1) m = fmaxf(m, __shfl_xor(m, off));
        float p = (lane < cnt) ? expf(e_lane - m) : 0.f;
        float ssum = p;
#pragma unroll
        for (int off = 32; off; off >>= 1) ssum += __shfl_xor(ssum, off);
        float p_self = expf(e_self - m);
        float inv = 1.f / (ssum + p_self);
        float alpha = p * inv;
        float acc = p_self * inv * bf2f(h[(size_t)node * DD + lane]);
        for (int j0 = 0; j0 < cnt; ++j0) {
            int ss = __shfl(s, j0);
            float aa = __shfl(alpha, j0);
            acc += aa * bf2f(h[(size_t)ss * DD + lane]);
        }
        out[(size_t)node * ldo + lane] = acc + bgv;
        return;
    }

    float m = e_self;
    for (int j = beg + lane; j < end; j += 64) {
        int s = csr_src[j];
        m = fmaxf(m, lrelu(as_[s] + adv));
    }
#pragma unroll
    for (int off = 32; off; off >>= 1) m = fmaxf(m, __shfl_xor(m, off));
    float ssum = 0.f;
    for (int j = beg + lane; j < end; j += 64) {
        int s = csr_src[j];
        ssum += expf(lrelu(as_[s] + adv) - m);
    }
#pragma unroll
    for (int off = 32; off; off >>= 1) ssum += __shfl_xor(ssum, off);
    ssum += expf(e_self - m);
    float inv = 1.f / ssum;
    float acc = expf(e_self - m) * inv * bf2f(h[(size_t)node * DD + lane]);
    for (int j0 = beg; j0 < end; j0 += 64) {
        int j = j0 + lane;
        int s = 0;
        float alpha = 0.f;
        if (j < end) {
            s = csr_src[j];
            alpha = expf(lrelu(as_[s] + adv) - m) * inv;
        }
        int c = end - j0;
        if (c > 64) c = 64;
        for (int t = 0; t < c; ++t) {
            int ss = __shfl(s, t);
            float aa = __shfl(alpha, t);
            acc += aa * bf2f(h[(size_t)ss * DD + lane]);
        }
    }
    out[(size_t)node * ldo + lane] = acc + bgv;
}

// ---------- GAT: TWO nodes per wave (one per 32-lane half, deg<=32 fast path) ----------
// Lane lh (0..31) of each half handles packed features {2lh, 2lh+1} (bf16x2 uint
// loads: 32 lanes cover the 128B row; one load inst serves both halves' rows).
// Cross-half transport: WAVE-UNIFORM-source __shfl of both halves' values + a
// per-half cndmask select. Divergent-index cross-lane transport raced in rounds
// 3-4 — do not reintroduce. Softmax butterflies use offsets <=16 (stay in-half).
__global__ __launch_bounds__(256) void k_gat(const int* __restrict__ csr_ptr,
                                             const int* __restrict__ csr_src,
                                             const unsigned short* __restrict__ h,
                                             const float* __restrict__ as_,
                                             const float* __restrict__ ad_,
                                             const float* __restrict__ bg,
                                             float* __restrict__ out, int ldo, int N) {
    int wave = threadIdx.x >> 6, lane = threadIdx.x & 63;
    int half = lane >> 5, lh = lane & 31;
    int nodeA = blockIdx.x * 8 + wave * 2;
    int node = nodeA + half;
    bool active = node < N;
    int beg = 0, cnt = 0;
    if (active) {
        beg = csr_ptr[node];
        cnt = csr_ptr[node + 1] - beg;
    }
    int ocnt = __shfl_xor(cnt, 32);
    int vmax = max(cnt, ocnt);  // wave-uniform

    if (vmax <= 32) {
        float adv = active ? ad_[node] : 0.f;
        float e_self = active ? lrelu(as_[node] + adv) : -3.0e38f;
        int s = 0;
        float e_lane = -3.0e38f;
        if (lh < cnt) {
            s = csr_src[beg + lh];
            e_lane = lrelu(as_[s] + adv);
        }
        float m = fmaxf(e_lane, e_self);
#pragma unroll
        for (int off = 16; off; off >>= 1) m = fmaxf(m, __shfl_xor(m, off));
        float p = (lh < cnt) ? expf(e_lane - m) : 0.f;
        float ssum = p;
#pragma unroll
        for (int off = 16; off; off >>= 1) ssum += __shfl_xor(ssum, off);
        float p_self = expf(e_self - m);
        float inv = 1.f / (ssum + p_self);
        float alpha = p * inv;

        float accx = 0.f, accy = 0.f;
        if (active) {
            unsigned int h2 = *(const unsigned int*)(h + (size_t)node * DD + lh * 2);
            float a_self = p_self * inv;
            accx = a_self * __uint_as_float(h2 << 16);
            accy = a_self * __uint_as_float(h2 & 0xffff0000u);
        }
        for (int j0 = 0; j0 < vmax; j0 += 4) {
#pragma unroll
            for (int u = 0; u < 4; u++) {
                int j = j0 + u;
                int sa = __shfl(s, j);          // uniform source lanes
                int sb = __shfl(s, j + 32);
                float aa = __shfl(alpha, j);
                float ab = __shfl(alpha, j + 32);
                int ss = half ? sb : sa;
                float av = half ? ab : aa;
                if (j < cnt) {
                    unsigned int h2 = *(const unsigned int*)(h + (size_t)ss * DD + lh * 2);
                    accx += av * __uint_as_float(h2 << 16);
                    accy += av * __uint_as_float(h2 & 0xffff0000u);
                }
            }
        }
        if (active) {
            int f0 = 2 * lh;
            float bx = bg[((f0 & 3) << 4) | (f0 >> 2)];        // pi^-1(2lh)
            float by = bg[(((f0 + 1) & 3) << 4) | (f0 >> 2)];  // pi^-1(2lh+1), (2lh+1)>>2==lh>>1==f0>>2
            float2 o;
            o.x = accx + bx;
            o.y = accy + by;
            *(float2*)(out + (size_t)node * ldo + f0) = o;
        }
        return;
    }

    // rare fallback: whole wave handles each node sequentially (proven path)
    float bgv = bg[((lane & 3) << 4) | (lane >> 2)];
    if (nodeA < N) gat_node_fullwave(nodeA, csr_ptr, csr_src, h, as_, ad_, bgv, out, ldo, lane);
    if (nodeA + 1 < N)
        gat_node_fullwave(nodeA + 1, csr_ptr, csr_src, h, as_, ad_, bgv, out, ldo, lane);
}

extern "C" void kernel_launch(void* const* d_in, const int* in_sizes, int n_in,
                              void* d_out, int out_size, void* d_ws, size_t ws_size,
                              hipStream_t stream) {
    const float* x = (const float*)d_in[0];
    const int* edges = (const int*)d_in[1];
    const float* Wg = (const float*)d_in[2];
    const float* a_src = (const float*)d_in[3];
    const float* a_dst = (const float*)d_in[4];
    const float* bg = (const float*)d_in[5];
    const float* W1 = (const float*)d_in[6];
    const float* b1 = (const float*)d_in[7];
    const float* W2 = (const float*)d_in[8];
    const float* b2 = (const float*)d_in[9];
    float* out = (float*)d_out;

    const int N = in_sizes[0] / DD;          // 100000
    const int E = in_sizes[1] / (2 * RREL);  // 1000000
    const int NB = (N + BSZ - 1) >> BSH;     // 98 buckets (requires N <= 131072)

    // workspace layout (256B aligned)
    size_t off = 0;
    auto alloc = [&](size_t bytes) {
        size_t o = off;
        off = (off + bytes + 255) & ~(size_t)255;
        return o;
    };
    char* ws = (char*)d_ws;
    float* combined = (float*)(ws + alloc((size_t)N * 320 * 4));
    unsigned short* h4 = (unsigned short*)(ws + alloc((size_t)4 * N * 64 * 2));  // also hid
    float* wsrc = (float*)(ws + alloc(LLAY * RREL * DD * 4));
    float* wdst = (float*)(ws + alloc(LLAY * RREL * DD * 4));
    unsigned short* WgT = (unsigned short*)(ws + alloc(8 * 4096 * 2));
    unsigned short* W1T = (unsigned short*)(ws + alloc(2 * 64 * 320 * 2));
    unsigned short* W2T = (unsigned short*)(ws + alloc(2 * 4096 * 2));
    int* btot = (int*)(ws + alloc((size_t)RREL * NB * 4));
    int* bucketoff = (int*)(ws + alloc((size_t)RREL * (NB + 1) * 4));
    int* bpos = (int*)(ws + alloc((size_t)RREL * NB * 4));
    unsigned int* packed = (unsigned int*)(ws + alloc((size_t)RREL * E * 4));  // also as4/ad4
    int* csr_ptr = (int*)(ws + alloc((size_t)RREL * (N + 1) * 4));
    int* csr_src = (int*)(ws + alloc((size_t)RREL * E * 4));
    (void)ws_size;
    unsigned short* hid = h4;     // h4 dead when hid is produced
    float* as4 = (float*)packed;  // packed dead after CSR build
    float* ad4 = as4 + (size_t)4 * N;

    const int ebblocks = (E + EPB - 1) / EPB;

    // --- preprocessing ---
    k_zero<<<dim3((RREL * NB + 255) / 256), dim3(256), 0, stream>>>(btot, RREL * NB);
    k_wvec<<<dim3(2), dim3(256), 0, stream>>>(Wg, a_src, a_dst, wsrc, wdst);
    k_prep<<<dim3(320), dim3(256), 0, stream>>>(Wg, W1, W2, WgT, W1T, W2T);
    k_copy_x<<<dim3((N * 16 + 255) / 256), dim3(256), 0, stream>>>(x, combined, N);
    k_bhist<<<dim3(ebblocks, RREL), dim3(256), 0, stream>>>(edges, btot, E, NB);
    k_bscan<<<dim3(1), dim3(64), 0, stream>>>(btot, bucketoff, bpos, csr_ptr, N, E, NB);
    k_binscatter<<<dim3(ebblocks, RREL), dim3(256), 0, stream>>>(edges, bpos, packed, E, NB);
    k_bucket_sort<<<dim3(NB, RREL), dim3(256), 0, stream>>>(packed, bucketoff, csr_ptr, csr_src,
                                                            N, E, NB);

    const int gemm_blocks = (N + 255) / 256;
    const int gat_blocks = (N + 7) / 8;

    for (int l = 0; l < LLAY; l++) {
        k_hgemm<<<dim3(gemm_blocks), dim3(256), 0, stream>>>(
            combined, WgT + (size_t)l * 4 * 4096, wsrc + l * 256, wdst + l * 256, h4, as4, ad4, N);
        for (int r = 0; r < RREL; r++) {
            k_gat<<<dim3(gat_blocks), dim3(256), 0, stream>>>(
                csr_ptr + (size_t)r * (N + 1), csr_src + (size_t)r * E, h4 + (size_t)r * N * 64,
                as4 + (size_t)r * N, ad4 + (size_t)r * N, bg + (size_t)(l * RREL + r) * DD,
                combined + 64 + 64 * r, 320, N);
        }
        k_w1gemm<<<dim3(gemm_blocks), dim3(256), 0, stream>>>(combined, W1T + (size_t)l * 20480,
                                                              b1 + l * DD, hid, N);
        float* dest = (l == LLAY - 1) ? out : combined;
        int ldd = (l == LLAY - 1) ? DD : 320;
        k_w2gemm<<<dim3(gemm_blocks), dim3(256), 0, stream>>>(hid, W2T + (size_t)l * 4096,
                                                              b2 + l * DD, dest, ldd, N);
    }
}

// Round 8
// 782.336 us; speedup vs baseline: 1.0440x; 1.0440x over previous
//
#include <hip/hip_runtime.h>
#include <hip/hip_bf16.h>
#include <math.h>

// Problem constants (from reference): D=64, L=2, R=4. N, E derived from sizes.
#define DD 64
#define RREL 4
#define LLAY 2
#define NEG_SLOPE 0.2f
#define EPB 4096   // edges per block in binning passes
#define BSH 10     // bucket shift: 1024 nodes per bucket
#define BSZ 1024

typedef __attribute__((ext_vector_type(8))) short short8;
typedef __attribute__((ext_vector_type(4))) short short4v;
typedef __attribute__((ext_vector_type(4))) float float4v;

__device__ __forceinline__ float lrelu(float x) { return x > 0.f ? x : NEG_SLOPE * x; }

// fp32 -> bf16 round-to-nearest-even (finite values)
__device__ __forceinline__ unsigned short f2bf(float f) {
    unsigned int u = __float_as_uint(f);
    return (unsigned short)((u + 0x7FFFu + ((u >> 16) & 1u)) >> 16);
}
__device__ __forceinline__ float bf2f(unsigned short u) {
    return __uint_as_float((unsigned int)u << 16);
}

// ---------- small precompute: wsrc/wdst = Wg @ a_src, Wg @ a_dst ----------
__global__ void k_wvec(const float* __restrict__ Wg, const float* __restrict__ asrc,
                       const float* __restrict__ adst, float* __restrict__ wsrc,
                       float* __restrict__ wdst) {
    int idx = blockIdx.x * blockDim.x + threadIdx.x;  // L*R*64 = 512
    if (idx >= LLAY * RREL * DD) return;
    int k = idx & 63;
    int lr = idx >> 6;
    const float* W = Wg + (size_t)lr * DD * DD;
    const float* as = asrc + lr * DD;
    const float* ad = adst + lr * DD;
    float s1 = 0.f, s2 = 0.f;
#pragma unroll
    for (int j = 0; j < DD; j++) {
        float w = W[k * DD + j];
        s1 += w * as[j];
        s2 += w * ad[j];
    }
    wsrc[idx] = s1;
    wdst[idx] = s2;
}

// ---------- weight prep: bf16, transposed [n][k]; W1 k-rows pi-permuted ----------
// pi(n) = (n&15)*4 + (n>>4)  (h-gemm packed-store column permutation)
// pi^-1(f) = (f&3)*16 + (f>>2)
__global__ void k_prep(const float* __restrict__ Wg, const float* __restrict__ W1,
                       const float* __restrict__ W2, unsigned short* __restrict__ WgT,
                       unsigned short* __restrict__ W1T, unsigned short* __restrict__ W2T) {
    int idx = blockIdx.x * blockDim.x + threadIdx.x;
    if (idx < 8 * 4096) {  // WgT[lr][n][k] = Wg[lr][k][n]  (k unpermuted: X side plain)
        int lr = idx >> 12, rem = idx & 4095, n = rem >> 6, k = rem & 63;
        WgT[idx] = f2bf(Wg[(size_t)lr * 4096 + k * 64 + n]);
    } else if (idx < 32768 + 2 * 64 * 320) {  // W1T[l][n][kk]
        int i = idx - 32768;
        int l = i / 20480, rem = i % 20480, n = rem / 320, kk = rem % 320;
        int src;
        if (kk < 64) src = kk;  // x-slice: unpermuted
        else {
            int r = (kk - 64) >> 6, f = (kk - 64) & 63;
            src = 64 + r * 64 + ((f & 3) * 16) + (f >> 2);  // h-slices: pi^-1
        }
        W1T[i] = f2bf(W1[(size_t)l * 20480 + src * 64 + n]);
    } else if (idx < 32768 + 40960 + 2 * 4096) {  // W2T[l][n][k] = W2[l][k][n]
        int i = idx - 73728;
        int l = i >> 12, rem = i & 4095, n = rem >> 6, k = rem & 63;
        W2T[i] = f2bf(W2[(size_t)l * 4096 + k * 64 + n]);
    }
}

// ---------- copy x into combined[:,0:64] (bf16, stride 320) ----------
__global__ void k_copy_x(const float* __restrict__ x, unsigned short* __restrict__ combined,
                         int N) {
    int i = blockIdx.x * blockDim.x + threadIdx.x;  // N*32 uints
    if (i >= N * 32) return;
    int row = i >> 5, c2 = i & 31;
    float2 v = *(const float2*)(x + (size_t)row * DD + c2 * 2);
    unsigned int p = (unsigned int)f2bf(v.x) | ((unsigned int)f2bf(v.y) << 16);
    *(unsigned int*)(combined + (size_t)row * 320 + c2 * 2) = p;
}

// ---------- zero int buffer ----------
__global__ void k_zero(int* __restrict__ p, int n) {
    int i = blockIdx.x * blockDim.x + threadIdx.x;
    if (i < n) p[i] = 0;
}

// ---------- CSR pass A0: coarse bucket histogram (LDS-privatized) ----------
__global__ __launch_bounds__(256) void k_bhist(const int* __restrict__ edges,
                                               int* __restrict__ btot, int E, int NB) {
    int r = blockIdx.y;
    int e0 = blockIdx.x * EPB;
    int t = threadIdx.x;
    __shared__ int lh[128];
    for (int i = t; i < 128; i += 256) lh[i] = 0;
    __syncthreads();
    const int* dstp = edges + (size_t)r * 2 * E + E;
#pragma unroll
    for (int i = 0; i < EPB / 256; i++) {
        int e = e0 + t + 256 * i;
        if (e < E) atomicAdd(&lh[dstp[e] >> BSH], 1);
    }
    __syncthreads();
    for (int i = t; i < NB; i += 256) {
        int c = lh[i];
        if (c) atomicAdd(&btot[r * NB + i], c);
    }
}

// ---------- CSR pass A1: serial scan of bucket totals (tiny) ----------
__global__ void k_bscan(const int* __restrict__ btot, int* __restrict__ bucketoff,
                        int* __restrict__ bpos, int* __restrict__ csr_ptr, int N, int E, int NB) {
    int r = threadIdx.x;
    if (r >= RREL) return;
    int run = 0;
    for (int b = 0; b < NB; b++) {
        bucketoff[r * (NB + 1) + b] = run;
        bpos[r * NB + b] = run;
        run += btot[r * NB + b];
    }
    bucketoff[r * (NB + 1) + NB] = run;  // == E
    csr_ptr[(size_t)r * (N + 1) + N] = E;
}

// ---------- CSR pass A2: block-aggregated bin scatter (dense writes) ----------
__global__ __launch_bounds__(256) void k_binscatter(const int* __restrict__ edges,
                                                    int* __restrict__ bpos,
                                                    unsigned int* __restrict__ packed, int E,
                                                    int NB) {
    int r = blockIdx.y;
    int e0 = blockIdx.x * EPB;
    int t = threadIdx.x;
    __shared__ int lh[128], lbase[128];
    for (int i = t; i < 128; i += 256) lh[i] = 0;
    __syncthreads();
    const int* srcp = edges + (size_t)r * 2 * E;
    const int* dstp = srcp + E;
    int md[EPB / 256], ms[EPB / 256];
#pragma unroll
    for (int i = 0; i < EPB / 256; i++) {
        int e = e0 + t + 256 * i;
        int d = -1, s = 0;
        if (e < E) {
            d = dstp[e];
            s = srcp[e];
            atomicAdd(&lh[d >> BSH], 1);
        }
        md[i] = d;
        ms[i] = s;
    }
    __syncthreads();
    for (int i = t; i < NB; i += 256) {
        int c = lh[i];
        lbase[i] = c ? atomicAdd(&bpos[r * NB + i], c) : 0;
        lh[i] = 0;
    }
    __syncthreads();
#pragma unroll
    for (int i = 0; i < EPB / 256; i++) {
        if (md[i] >= 0) {
            int b = md[i] >> BSH;
            int p = lbase[b] + atomicAdd(&lh[b], 1);
            packed[(size_t)r * E + p] =
                ((unsigned int)(md[i] & (BSZ - 1)) << 17) | (unsigned int)ms[i];
        }
    }
}

// ---------- CSR pass B: per-bucket counting sort (L2-local) + csr_ptr ----------
__global__ __launch_bounds__(256) void k_bucket_sort(const unsigned int* __restrict__ packed,
                                                     const int* __restrict__ bucketoff,
                                                     int* __restrict__ csr_ptr,
                                                     int* __restrict__ csr_src, int N, int E,
                                                     int NB) {
    int r = blockIdx.y, b = blockIdx.x;
    int t = threadIdx.x;
    __shared__ int pos[BSZ];
    __shared__ int tsum[256];
    int base = bucketoff[r * (NB + 1) + b];
    int cnt = bucketoff[r * (NB + 1) + b + 1] - base;
    const unsigned int* pk = packed + (size_t)r * E + base;
    for (int i = t; i < BSZ; i += 256) pos[i] = 0;
    __syncthreads();
    for (int i = t; i < cnt; i += 256) atomicAdd(&pos[pk[i] >> 17], 1);
    __syncthreads();
    int v[4];
    int s = 0;
#pragma unroll
    for (int i = 0; i < 4; i++) {
        v[i] = pos[t * 4 + i];
        s += v[i];
    }
    tsum[t] = s;
    __syncthreads();
    for (int off = 1; off < 256; off <<= 1) {
        int add = (t >= off) ? tsum[t - off] : 0;
        __syncthreads();
        tsum[t] += add;
        __syncthreads();
    }
    int run = tsum[t] - s;  // exclusive
    __syncthreads();
#pragma unroll
    for (int i = 0; i < 4; i++) {
        int node_l = t * 4 + i;
        pos[node_l] = run;
        int node = b * BSZ + node_l;
        if (node < N) csr_ptr[(size_t)r * (N + 1) + node] = base + run;
        run += v[i];
    }
    __syncthreads();
    for (int i = t; i < cnt; i += 256) {
        unsigned int p = pk[i];
        int d = p >> 17;
        int sidx = p & 0x1FFFF;
        int loc = atomicAdd(&pos[d], 1);
        csr_src[(size_t)r * E + base + loc] = sidx;
    }
}

// ======== MFMA GEMM kernels: M-tile 256 (4 waves x 64 rows), N=64, 16x16x32 bf16 ========

// ---------- fused h-gemm: h_r = X@Wg_r (bf16, pi-packed), as/ad = X@wvec ----------
__global__ __launch_bounds__(256, 3) void k_hgemm(const unsigned short* __restrict__ X,
                                                  const unsigned short* __restrict__ WgTl,
                                                  const float* __restrict__ wsrcl,
                                                  const float* __restrict__ wdstl,
                                                  unsigned short* __restrict__ h4,
                                                  float* __restrict__ as4,
                                                  float* __restrict__ ad4, int N) {
    __shared__ __align__(16) unsigned short Xb[256][72];
    __shared__ __align__(16) unsigned short Wb[64][72];
    __shared__ float wsS[4][64], wdS[4][64];
    int tid = threadIdx.x, wave = tid >> 6, lane = tid & 63;
    int l15 = lane & 15, q = lane >> 4;
    int row0 = blockIdx.x * 256;
#pragma unroll
    for (int i = 0; i < 8; i++) {
        int f = tid + 256 * i;
        int rr = f >> 3, seg = f & 7;
        int grow = row0 + rr;
        short8 v = (short8){0, 0, 0, 0, 0, 0, 0, 0};
        if (grow < N) v = *(const short8*)(X + (size_t)grow * 320 + seg * 8);
        *(short8*)&Xb[rr][seg * 8] = v;
    }
    wsS[tid >> 6][tid & 63] = wsrcl[tid];
    wdS[tid >> 6][tid & 63] = wdstl[tid];
    __syncthreads();
    short8 afr[4][2];
#pragma unroll
    for (int mt = 0; mt < 4; mt++)
#pragma unroll
        for (int ks = 0; ks < 2; ks++)
            afr[mt][ks] = *(const short8*)&Xb[wave * 64 + mt * 16 + l15][ks * 32 + q * 8];
    {
        int grow = row0 + tid;
        float s[4] = {0.f, 0.f, 0.f, 0.f}, d[4] = {0.f, 0.f, 0.f, 0.f};
#pragma unroll
        for (int seg = 0; seg < 8; seg++) {
            short8 v = *(const short8*)&Xb[tid][seg * 8];
#pragma unroll
            for (int j = 0; j < 8; j++) {
                float xv = bf2f((unsigned short)v[j]);
                int k = seg * 8 + j;
#pragma unroll
                for (int r = 0; r < 4; r++) {
                    s[r] += xv * wsS[r][k];
                    d[r] += xv * wdS[r][k];
                }
            }
        }
        if (grow < N) {
#pragma unroll
            for (int r = 0; r < 4; r++) {
                as4[(size_t)r * N + grow] = s[r];
                ad4[(size_t)r * N + grow] = d[r];
            }
        }
    }
    for (int r = 0; r < 4; r++) {
        __syncthreads();
#pragma unroll
        for (int i = 0; i < 2; i++) {
            int f = tid + 256 * i;
            int n = f >> 3, seg = f & 7;
            *(short8*)&Wb[n][seg * 8] = *(const short8*)(WgTl + r * 4096 + n * 64 + seg * 8);
        }
        __syncthreads();
        short8 bfr[4][2];
#pragma unroll
        for (int nt = 0; nt < 4; nt++)
#pragma unroll
            for (int ks = 0; ks < 2; ks++)
                bfr[nt][ks] = *(const short8*)&Wb[nt * 16 + l15][ks * 32 + q * 8];
        float4v acc[4][4];
#pragma unroll
        for (int mt = 0; mt < 4; mt++)
#pragma unroll
            for (int nt = 0; nt < 4; nt++) acc[mt][nt] = (float4v){0.f, 0.f, 0.f, 0.f};
#pragma unroll
        for (int mt = 0; mt < 4; mt++)
#pragma unroll
            for (int nt = 0; nt < 4; nt++) {
                acc[mt][nt] = __builtin_amdgcn_mfma_f32_16x16x32_bf16(afr[mt][0], bfr[nt][0],
                                                                     acc[mt][nt], 0, 0, 0);
                acc[mt][nt] = __builtin_amdgcn_mfma_f32_16x16x32_bf16(afr[mt][1], bfr[nt][1],
                                                                     acc[mt][nt], 0, 0, 0);
            }
        unsigned short* hr = h4 + (size_t)r * N * 64;
#pragma unroll
        for (int mt = 0; mt < 4; mt++) {
            int rowb = row0 + wave * 64 + mt * 16 + q * 4;
#pragma unroll
            for (int reg = 0; reg < 4; reg++) {
                int row = rowb + reg;
                if (row < N) {
                    short4v sv;
                    sv[0] = (short)f2bf(acc[mt][0][reg]);
                    sv[1] = (short)f2bf(acc[mt][1][reg]);
                    sv[2] = (short)f2bf(acc[mt][2][reg]);
                    sv[3] = (short)f2bf(acc[mt][3][reg]);
                    *(short4v*)&hr[(size_t)row * 64 + l15 * 4] = sv;
                }
            }
        }
    }
}

// ---------- W1 gemm: hid = tanh(combined[N,320](bf16) @ W1 + b1), bf16 out ----------
__global__ __launch_bounds__(256, 3) void k_w1gemm(const unsigned short* __restrict__ X,
                                                   const unsigned short* __restrict__ WT,
                                                   const float* __restrict__ bias,
                                                   unsigned short* __restrict__ Y, int N) {
    __shared__ __align__(16) unsigned short Xb[256][72];
    __shared__ __align__(16) unsigned short Wb[64][72];
    int tid = threadIdx.x, wave = tid >> 6, lane = tid & 63;
    int l15 = lane & 15, q = lane >> 4;
    int row0 = blockIdx.x * 256;
    float4v acc[4][4];
#pragma unroll
    for (int mt = 0; mt < 4; mt++)
#pragma unroll
        for (int nt = 0; nt < 4; nt++) acc[mt][nt] = (float4v){0.f, 0.f, 0.f, 0.f};
    for (int kc = 0; kc < 320; kc += 64) {
        __syncthreads();
#pragma unroll
        for (int i = 0; i < 8; i++) {
            int f = tid + 256 * i;
            int rr = f >> 3, seg = f & 7;
            int grow = row0 + rr;
            short8 v = (short8){0, 0, 0, 0, 0, 0, 0, 0};
            if (grow < N) v = *(const short8*)(X + (size_t)grow * 320 + kc + seg * 8);
            *(short8*)&Xb[rr][seg * 8] = v;
        }
#pragma unroll
        for (int i = 0; i < 2; i++) {
            int f = tid + 256 * i;
            int n = f >> 3, seg = f & 7;
            *(short8*)&Wb[n][seg * 8] = *(const short8*)(WT + n * 320 + kc + seg * 8);
        }
        __syncthreads();
        short8 bfr[4][2];
#pragma unroll
        for (int nt = 0; nt < 4; nt++)
#pragma unroll
            for (int ks = 0; ks < 2; ks++)
                bfr[nt][ks] = *(const short8*)&Wb[nt * 16 + l15][ks * 32 + q * 8];
#pragma unroll
        for (int mt = 0; mt < 4; mt++) {
            short8 a0 = *(const short8*)&Xb[wave * 64 + mt * 16 + l15][q * 8];
            short8 a1 = *(const short8*)&Xb[wave * 64 + mt * 16 + l15][32 + q * 8];
#pragma unroll
            for (int nt = 0; nt < 4; nt++) {
                acc[mt][nt] =
                    __builtin_amdgcn_mfma_f32_16x16x32_bf16(a0, bfr[nt][0], acc[mt][nt], 0, 0, 0);
                acc[mt][nt] =
                    __builtin_amdgcn_mfma_f32_16x16x32_bf16(a1, bfr[nt][1], acc[mt][nt], 0, 0, 0);
            }
        }
    }
#pragma unroll
    for (int mt = 0; mt < 4; mt++) {
        int rowb = row0 + wave * 64 + mt * 16 + q * 4;
#pragma unroll
        for (int reg = 0; reg < 4; reg++) {
            int row = rowb + reg;
            if (row < N) {
#pragma unroll
                for (int nt = 0; nt < 4; nt++) {
                    int n = nt * 16 + l15;
                    float v = tanhf(acc[mt][nt][reg] + bias[n]);
                    Y[(size_t)row * 64 + n] = f2bf(v);
                }
            }
        }
    }
}

// ---------- W2 gemm: dest = hid[N,64](bf16) @ W2 + b2; bf16 (layer0) or fp32 out ----------
template <bool BFOUT>
__global__ __launch_bounds__(256, 3) void k_w2gemm(const unsigned short* __restrict__ X,
                                                   const unsigned short* __restrict__ WT,
                                                   const float* __restrict__ bias,
                                                   unsigned short* __restrict__ Ybf,
                                                   float* __restrict__ Yf, int ldy, int N) {
    __shared__ __align__(16) unsigned short Xb[256][72];
    __shared__ __align__(16) unsigned short Wb[64][72];
    int tid = threadIdx.x, wave = tid >> 6, lane = tid & 63;
    int l15 = lane & 15, q = lane >> 4;
    int row0 = blockIdx.x * 256;
#pragma unroll
    for (int i = 0; i < 8; i++) {
        int f = tid + 256 * i;
        int rr = f >> 3, seg = f & 7;
        int grow = row0 + rr;
        short8 v = (short8){0, 0, 0, 0, 0, 0, 0, 0};
        if (grow < N) v = *(const short8*)(X + (size_t)grow * 64 + seg * 8);
        *(short8*)&Xb[rr][seg * 8] = v;
    }
#pragma unroll
    for (int i = 0; i < 2; i++) {
        int f = tid + 256 * i;
        int n = f >> 3, seg = f & 7;
        *(short8*)&Wb[n][seg * 8] = *(const short8*)(WT + n * 64 + seg * 8);
    }
    __syncthreads();
    short8 bfr[4][2];
#pragma unroll
    for (int nt = 0; nt < 4; nt++)
#pragma unroll
        for (int ks = 0; ks < 2; ks++)
            bfr[nt][ks] = *(const short8*)&Wb[nt * 16 + l15][ks * 32 + q * 8];
    float4v acc[4][4];
#pragma unroll
    for (int mt = 0; mt < 4; mt++)
#pragma unroll
        for (int nt = 0; nt < 4; nt++) acc[mt][nt] = (float4v){0.f, 0.f, 0.f, 0.f};
#pragma unroll
    for (int mt = 0; mt < 4; mt++) {
        short8 a0 = *(const short8*)&Xb[wave * 64 + mt * 16 + l15][q * 8];
        short8 a1 = *(const short8*)&Xb[wave * 64 + mt * 16 + l15][32 + q * 8];
#pragma unroll
        for (int nt = 0; nt < 4; nt++) {
            acc[mt][nt] =
                __builtin_amdgcn_mfma_f32_16x16x32_bf16(a0, bfr[nt][0], acc[mt][nt], 0, 0, 0);
            acc[mt][nt] =
                __builtin_amdgcn_mfma_f32_16x16x32_bf16(a1, bfr[nt][1], acc[mt][nt], 0, 0, 0);
        }
    }
#pragma unroll
    for (int mt = 0; mt < 4; mt++) {
        int rowb = row0 + wave * 64 + mt * 16 + q * 4;
#pragma unroll
        for (int reg = 0; reg < 4; reg++) {
            int row = rowb + reg;
            if (row < N) {
#pragma unroll
                for (int nt = 0; nt < 4; nt++) {
                    int n = nt * 16 + l15;
                    float v = acc[mt][nt][reg] + bias[n];
                    if (BFOUT)
                        Ybf[(size_t)row * ldy + n] = f2bf(v);
                    else
                        Yf[(size_t)row * ldy + n] = v;
                }
            }
        }
    }
}

// ---------- full-wave per-node GAT (proven path; rare fallback, bf16 out) ----------
__device__ void gat_node_fullwave(int node, const int* __restrict__ csr_ptr,
                                  const int* __restrict__ csr_src,
                                  const unsigned short* __restrict__ h,
                                  const float* __restrict__ as_,
                                  const float* __restrict__ ad_, float bgv,
                                  unsigned short* __restrict__ out, int ldo, int lane) {
    float adv = ad_[node];
    float e_self = lrelu(as_[node] + adv);
    int beg = csr_ptr[node], end = csr_ptr[node + 1];
    int cnt = end - beg;

    if (cnt <= 64) {
        int s = 0;
        float e_lane = -3.0e38f;
        if (lane < cnt) {
            s = csr_src[beg + lane];
            e_lane = lrelu(as_[s] + adv);
        }
        float m = fmaxf(e_lane, e_self);
#pragma unroll
        for (int off = 32; off; off >>= 1) m = fmaxf(m, __shfl_xor(m, off));
        float p = (lane < cnt) ? expf(e_lane - m) : 0.f;
        float ssum = p;
#pragma unroll
        for (int off = 32; off; off >>= 1) ssum += __shfl_xor(ssum, off);
        float p_self = expf(e_self - m);
        float inv = 1.f / (ssum + p_self);
        float alpha = p * inv;
        float acc = p_self * inv * bf2f(h[(size_t)node * DD + lane]);
        for (int j0 = 0; j0 < cnt; ++j0) {
            int ss = __shfl(s, j0);
            float aa = __shfl(alpha, j0);
            acc += aa * bf2f(h[(size_t)ss * DD + lane]);
        }
        out[(size_t)node * ldo + lane] = f2bf(acc + bgv);
        return;
    }

    float m = e_self;
    for (int j = beg + lane; j < end; j += 64) {
        int s = csr_src[j];
        m = fmaxf(m, lrelu(as_[s] + adv));
    }
#pragma unroll
    for (int off = 32; off; off >>= 1) m = fmaxf(m, __shfl_xor(m, off));
    float ssum = 0.f;
    for (int j = beg + lane; j < end; j += 64) {
        int s = csr_src[j];
        ssum += expf(lrelu(as_[s] + adv) - m);
    }
#pragma unroll
    for (int off = 32; off; off >>= 1) ssum += __shfl_xor(ssum, off);
    ssum += expf(e_self - m);
    float inv = 1.f / ssum;
    float acc = expf(e_self - m) * inv * bf2f(h[(size_t)node * DD + lane]);
    for (int j0 = beg; j0 < end; j0 += 64) {
        int j = j0 + lane;
        int s = 0;
        float alpha = 0.f;
        if (j < end) {
            s = csr_src[j];
            alpha = expf(lrelu(as_[s] + adv) - m) * inv;
        }
        int c = end - j0;
        if (c > 64) c = 64;
        for (int t = 0; t < c; ++t) {
            int ss = __shfl(s, t);
            float aa = __shfl(alpha, t);
            acc += aa * bf2f(h[(size_t)ss * DD + lane]);
        }
    }
    out[(size_t)node * ldo + lane] = f2bf(acc + bgv);
}

// ---------- GAT: TWO nodes per wave, aggregation unrolled x8 (16 edges in flight) ----------
// Cross-half transport: WAVE-UNIFORM-source __shfl + per-half cndmask only.
// Divergent-index cross-lane transport raced in rounds 3-4 — do not reintroduce.
__global__ __launch_bounds__(256) void k_gat(const int* __restrict__ csr_ptr,
                                             const int* __restrict__ csr_src,
                                             const unsigned short* __restrict__ h,
                                             const float* __restrict__ as_,
                                             const float* __restrict__ ad_,
                                             const float* __restrict__ bg,
                                             unsigned short* __restrict__ out, int ldo, int N) {
    int wave = threadIdx.x >> 6, lane = threadIdx.x & 63;
    int half = lane >> 5, lh = lane & 31;
    int nodeA = blockIdx.x * 8 + wave * 2;
    int node = nodeA + half;
    bool active = node < N;
    int beg = 0, cnt = 0;
    if (active) {
        beg = csr_ptr[node];
        cnt = csr_ptr[node + 1] - beg;
    }
    int ocnt = __shfl_xor(cnt, 32);
    int vmax = max(cnt, ocnt);  // wave-uniform

    if (vmax <= 32) {
        float adv = active ? ad_[node] : 0.f;
        float e_self = active ? lrelu(as_[node] + adv) : -3.0e38f;
        int s = 0;
        float e_lane = -3.0e38f;
        if (lh < cnt) {
            s = csr_src[beg + lh];
            e_lane = lrelu(as_[s] + adv);
        }
        float m = fmaxf(e_lane, e_self);
#pragma unroll
        for (int off = 16; off; off >>= 1) m = fmaxf(m, __shfl_xor(m, off));
        float p = (lh < cnt) ? expf(e_lane - m) : 0.f;
        float ssum = p;
#pragma unroll
        for (int off = 16; off; off >>= 1) ssum += __shfl_xor(ssum, off);
        float p_self = expf(e_self - m);
        float inv = 1.f / (ssum + p_self);
        float alpha = p * inv;

        float accx = 0.f, accy = 0.f;
        if (active) {
            unsigned int h2 = *(const unsigned int*)(h + (size_t)node * DD + lh * 2);
            float a_self = p_self * inv;
            accx = a_self * __uint_as_float(h2 << 16);
            accy = a_self * __uint_as_float(h2 & 0xffff0000u);
        }
        for (int j0 = 0; j0 < vmax; j0 += 8) {
#pragma unroll
            for (int u = 0; u < 8; u++) {
                int j = j0 + u;
                int sa = __shfl(s, j);  // uniform source lanes
                int sb = __shfl(s, j + 32);
                float aa = __shfl(alpha, j);
                float ab = __shfl(alpha, j + 32);
                int ss = half ? sb : sa;
                float av = half ? ab : aa;
                if (j < cnt) {
                    unsigned int h2 = *(const unsigned int*)(h + (size_t)ss * DD + lh * 2);
                    accx += av * __uint_as_float(h2 << 16);
                    accy += av * __uint_as_float(h2 & 0xffff0000u);
                }
            }
        }
        if (active) {
            int f0 = 2 * lh;
            float bx = bg[((f0 & 3) << 4) | (f0 >> 2)];        // pi^-1(2lh)
            float by = bg[(((f0 + 1) & 3) << 4) | (f0 >> 2)];  // pi^-1(2lh+1)
            unsigned int pck =
                (unsigned int)f2bf(accx + bx) | ((unsigned int)f2bf(accy + by) << 16);
            *(unsigned int*)(out + (size_t)node * ldo + f0) = pck;
        }
        return;
    }

    // rare fallback: whole wave handles each node sequentially (proven path)
    float bgv = bg[((lane & 3) << 4) | (lane >> 2)];
    if (nodeA < N) gat_node_fullwave(nodeA, csr_ptr, csr_src, h, as_, ad_, bgv, out, ldo, lane);
    if (nodeA + 1 < N)
        gat_node_fullwave(nodeA + 1, csr_ptr, csr_src, h, as_, ad_, bgv, out, ldo, lane);
}

extern "C" void kernel_launch(void* const* d_in, const int* in_sizes, int n_in,
                              void* d_out, int out_size, void* d_ws, size_t ws_size,
                              hipStream_t stream) {
    const float* x = (const float*)d_in[0];
    const int* edges = (const int*)d_in[1];
    const float* Wg = (const float*)d_in[2];
    const float* a_src = (const float*)d_in[3];
    const float* a_dst = (const float*)d_in[4];
    const float* bg = (const float*)d_in[5];
    const float* W1 = (const float*)d_in[6];
    const float* b1 = (const float*)d_in[7];
    const float* W2 = (const float*)d_in[8];
    const float* b2 = (const float*)d_in[9];
    float* out = (float*)d_out;

    const int N = in_sizes[0] / DD;          // 100000
    const int E = in_sizes[1] / (2 * RREL);  // 1000000
    const int NB = (N + BSZ - 1) >> BSH;     // 98 buckets (requires N <= 131072)

    // workspace layout (256B aligned)
    size_t off = 0;
    auto alloc = [&](size_t bytes) {
        size_t o = off;
        off = (off + bytes + 255) & ~(size_t)255;
        return o;
    };
    char* ws = (char*)d_ws;
    unsigned short* combined = (unsigned short*)(ws + alloc((size_t)N * 320 * 2));  // bf16
    unsigned short* h4 = (unsigned short*)(ws + alloc((size_t)4 * N * 64 * 2));     // also hid
    float* wsrc = (float*)(ws + alloc(LLAY * RREL * DD * 4));
    float* wdst = (float*)(ws + alloc(LLAY * RREL * DD * 4));
    unsigned short* WgT = (unsigned short*)(ws + alloc(8 * 4096 * 2));
    unsigned short* W1T = (unsigned short*)(ws + alloc(2 * 64 * 320 * 2));
    unsigned short* W2T = (unsigned short*)(ws + alloc(2 * 4096 * 2));
    int* btot = (int*)(ws + alloc((size_t)RREL * NB * 4));
    int* bucketoff = (int*)(ws + alloc((size_t)RREL * (NB + 1) * 4));
    int* bpos = (int*)(ws + alloc((size_t)RREL * NB * 4));
    unsigned int* packed = (unsigned int*)(ws + alloc((size_t)RREL * E * 4));  // also as4/ad4
    int* csr_ptr = (int*)(ws + alloc((size_t)RREL * (N + 1) * 4));
    int* csr_src = (int*)(ws + alloc((size_t)RREL * E * 4));
    (void)ws_size;
    unsigned short* hid = h4;     // h4 dead when hid is produced
    float* as4 = (float*)packed;  // packed dead after CSR build
    float* ad4 = as4 + (size_t)4 * N;

    const int ebblocks = (E + EPB - 1) / EPB;

    // --- preprocessing ---
    k_zero<<<dim3((RREL * NB + 255) / 256), dim3(256), 0, stream>>>(btot, RREL * NB);
    k_wvec<<<dim3(2), dim3(256), 0, stream>>>(Wg, a_src, a_dst, wsrc, wdst);
    k_prep<<<dim3(320), dim3(256), 0, stream>>>(Wg, W1, W2, WgT, W1T, W2T);
    k_copy_x<<<dim3((N * 32 + 255) / 256), dim3(256), 0, stream>>>(x, combined, N);
    k_bhist<<<dim3(ebblocks, RREL), dim3(256), 0, stream>>>(edges, btot, E, NB);
    k_bscan<<<dim3(1), dim3(64), 0, stream>>>(btot, bucketoff, bpos, csr_ptr, N, E, NB);
    k_binscatter<<<dim3(ebblocks, RREL), dim3(256), 0, stream>>>(edges, bpos, packed, E, NB);
    k_bucket_sort<<<dim3(NB, RREL), dim3(256), 0, stream>>>(packed, bucketoff, csr_ptr, csr_src,
                                                            N, E, NB);

    const int gemm_blocks = (N + 255) / 256;
    const int gat_blocks = (N + 7) / 8;

    for (int l = 0; l < LLAY; l++) {
        k_hgemm<<<dim3(gemm_blocks), dim3(256), 0, stream>>>(
            combined, WgT + (size_t)l * 4 * 4096, wsrc + l * 256, wdst + l * 256, h4, as4, ad4, N);
        for (int r = 0; r < RREL; r++) {
            k_gat<<<dim3(gat_blocks), dim3(256), 0, stream>>>(
                csr_ptr + (size_t)r * (N + 1), csr_src + (size_t)r * E, h4 + (size_t)r * N * 64,
                as4 + (size_t)r * N, ad4 + (size_t)r * N, bg + (size_t)(l * RREL + r) * DD,
                combined + 64 + 64 * r, 320, N);
        }
        k_w1gemm<<<dim3(gemm_blocks), dim3(256), 0, stream>>>(combined, W1T + (size_t)l * 20480,
                                                              b1 + l * DD, hid, N);
        if (l == LLAY - 1) {
            k_w2gemm<false><<<dim3(gemm_blocks), dim3(256), 0, stream>>>(
                hid, W2T + (size_t)l * 4096, b2 + l * DD, nullptr, out, DD, N);
        } else {
            k_w2gemm<true><<<dim3(gemm_blocks), dim3(256), 0, stream>>>(
                hid, W2T + (size_t)l * 4096, b2 + l * DD, combined, nullptr, 320, N);
        }
    }
}

// Round 9
// 773.714 us; speedup vs baseline: 1.0557x; 1.0111x over previous
//
#include <hip/hip_runtime.h>
#include <hip/hip_bf16.h>
#include <math.h>

// Problem constants (from reference): D=64, L=2, R=4. N, E derived from sizes.
#define DD 64
#define RREL 4
#define LLAY 2
#define NEG_SLOPE 0.2f
#define EPB 4096   // edges per block in binning passes
#define BSH 10     // bucket shift: 1024 nodes per bucket
#define BSZ 1024

typedef __attribute__((ext_vector_type(8))) short short8;
typedef __attribute__((ext_vector_type(4))) short short4v;
typedef __attribute__((ext_vector_type(4))) float float4v;

__device__ __forceinline__ float lrelu(float x) { return x > 0.f ? x : NEG_SLOPE * x; }

// fp32 -> bf16 round-to-nearest-even (finite values)
__device__ __forceinline__ unsigned short f2bf(float f) {
    unsigned int u = __float_as_uint(f);
    return (unsigned short)((u + 0x7FFFu + ((u >> 16) & 1u)) >> 16);
}
__device__ __forceinline__ float bf2f(unsigned short u) {
    return __uint_as_float((unsigned int)u << 16);
}

// ---------- small precompute: wsrc/wdst = Wg @ a_src, Wg @ a_dst ----------
__global__ void k_wvec(const float* __restrict__ Wg, const float* __restrict__ asrc,
                       const float* __restrict__ adst, float* __restrict__ wsrc,
                       float* __restrict__ wdst) {
    int idx = blockIdx.x * blockDim.x + threadIdx.x;  // L*R*64 = 512
    if (idx >= LLAY * RREL * DD) return;
    int k = idx & 63;
    int lr = idx >> 6;
    const float* W = Wg + (size_t)lr * DD * DD;
    const float* as = asrc + lr * DD;
    const float* ad = adst + lr * DD;
    float s1 = 0.f, s2 = 0.f;
#pragma unroll
    for (int j = 0; j < DD; j++) {
        float w = W[k * DD + j];
        s1 += w * as[j];
        s2 += w * ad[j];
    }
    wsrc[idx] = s1;
    wdst[idx] = s2;
}

// ---------- weight prep: bf16, transposed [n][k]; W1 k-rows pi-permuted ----------
// pi(n) = (n&15)*4 + (n>>4)  (h-gemm packed-store column permutation)
// pi^-1(f) = (f&3)*16 + (f>>2)
__global__ void k_prep(const float* __restrict__ Wg, const float* __restrict__ W1,
                       const float* __restrict__ W2, unsigned short* __restrict__ WgT,
                       unsigned short* __restrict__ W1T, unsigned short* __restrict__ W2T) {
    int idx = blockIdx.x * blockDim.x + threadIdx.x;
    if (idx < 8 * 4096) {  // WgT[lr][n][k] = Wg[lr][k][n]
        int lr = idx >> 12, rem = idx & 4095, n = rem >> 6, k = rem & 63;
        WgT[idx] = f2bf(Wg[(size_t)lr * 4096 + k * 64 + n]);
    } else if (idx < 32768 + 2 * 64 * 320) {  // W1T[l][n][kk]
        int i = idx - 32768;
        int l = i / 20480, rem = i % 20480, n = rem / 320, kk = rem % 320;
        int src;
        if (kk < 64) src = kk;  // x-slice: unpermuted
        else {
            int r = (kk - 64) >> 6, f = (kk - 64) & 63;
            src = 64 + r * 64 + ((f & 3) * 16) + (f >> 2);  // h-slices: pi^-1
        }
        W1T[i] = f2bf(W1[(size_t)l * 20480 + src * 64 + n]);
    } else if (idx < 32768 + 40960 + 2 * 4096) {  // W2T[l][n][k] = W2[l][k][n]
        int i = idx - 73728;
        int l = i >> 12, rem = i & 4095, n = rem >> 6, k = rem & 63;
        W2T[i] = f2bf(W2[(size_t)l * 4096 + k * 64 + n]);
    }
}

// ---------- copy x into combined[:,0:64] (bf16, stride 320) ----------
__global__ void k_copy_x(const float* __restrict__ x, unsigned short* __restrict__ combined,
                         int N) {
    int i = blockIdx.x * blockDim.x + threadIdx.x;  // N*32 uints
    if (i >= N * 32) return;
    int row = i >> 5, c2 = i & 31;
    float2 v = *(const float2*)(x + (size_t)row * DD + c2 * 2);
    unsigned int p = (unsigned int)f2bf(v.x) | ((unsigned int)f2bf(v.y) << 16);
    *(unsigned int*)(combined + (size_t)row * 320 + c2 * 2) = p;
}

// ---------- zero int buffer ----------
__global__ void k_zero(int* __restrict__ p, int n) {
    int i = blockIdx.x * blockDim.x + threadIdx.x;
    if (i < n) p[i] = 0;
}

// ---------- CSR pass A0: coarse bucket histogram (LDS-privatized) ----------
__global__ __launch_bounds__(256) void k_bhist(const int* __restrict__ edges,
                                               int* __restrict__ btot, int E, int NB) {
    int r = blockIdx.y;
    int e0 = blockIdx.x * EPB;
    int t = threadIdx.x;
    __shared__ int lh[128];
    for (int i = t; i < 128; i += 256) lh[i] = 0;
    __syncthreads();
    const int* dstp = edges + (size_t)r * 2 * E + E;
#pragma unroll
    for (int i = 0; i < EPB / 256; i++) {
        int e = e0 + t + 256 * i;
        if (e < E) atomicAdd(&lh[dstp[e] >> BSH], 1);
    }
    __syncthreads();
    for (int i = t; i < NB; i += 256) {
        int c = lh[i];
        if (c) atomicAdd(&btot[r * NB + i], c);
    }
}

// ---------- CSR pass A1: serial scan of bucket totals (tiny) ----------
__global__ void k_bscan(const int* __restrict__ btot, int* __restrict__ bucketoff,
                        int* __restrict__ bpos, int* __restrict__ csr_ptr, int N, int E, int NB) {
    int r = threadIdx.x;
    if (r >= RREL) return;
    int run = 0;
    for (int b = 0; b < NB; b++) {
        bucketoff[r * (NB + 1) + b] = run;
        bpos[r * NB + b] = run;
        run += btot[r * NB + b];
    }
    bucketoff[r * (NB + 1) + NB] = run;  // == E
    csr_ptr[(size_t)r * (N + 1) + N] = E;
}

// ---------- CSR pass A2: block-aggregated bin scatter (dense writes) ----------
__global__ __launch_bounds__(256) void k_binscatter(const int* __restrict__ edges,
                                                    int* __restrict__ bpos,
                                                    unsigned int* __restrict__ packed, int E,
                                                    int NB) {
    int r = blockIdx.y;
    int e0 = blockIdx.x * EPB;
    int t = threadIdx.x;
    __shared__ int lh[128], lbase[128];
    for (int i = t; i < 128; i += 256) lh[i] = 0;
    __syncthreads();
    const int* srcp = edges + (size_t)r * 2 * E;
    const int* dstp = srcp + E;
    int md[EPB / 256], ms[EPB / 256];
#pragma unroll
    for (int i = 0; i < EPB / 256; i++) {
        int e = e0 + t + 256 * i;
        int d = -1, s = 0;
        if (e < E) {
            d = dstp[e];
            s = srcp[e];
            atomicAdd(&lh[d >> BSH], 1);
        }
        md[i] = d;
        ms[i] = s;
    }
    __syncthreads();
    for (int i = t; i < NB; i += 256) {
        int c = lh[i];
        lbase[i] = c ? atomicAdd(&bpos[r * NB + i], c) : 0;
        lh[i] = 0;
    }
    __syncthreads();
#pragma unroll
    for (int i = 0; i < EPB / 256; i++) {
        if (md[i] >= 0) {
            int b = md[i] >> BSH;
            int p = lbase[b] + atomicAdd(&lh[b], 1);
            packed[(size_t)r * E + p] =
                ((unsigned int)(md[i] & (BSZ - 1)) << 17) | (unsigned int)ms[i];
        }
    }
}

// ---------- CSR pass B: per-bucket counting sort (L2-local) + csr_ptr ----------
__global__ __launch_bounds__(256) void k_bucket_sort(const unsigned int* __restrict__ packed,
                                                     const int* __restrict__ bucketoff,
                                                     int* __restrict__ csr_ptr,
                                                     int* __restrict__ csr_src, int N, int E,
                                                     int NB) {
    int r = blockIdx.y, b = blockIdx.x;
    int t = threadIdx.x;
    __shared__ int pos[BSZ];
    __shared__ int tsum[256];
    int base = bucketoff[r * (NB + 1) + b];
    int cnt = bucketoff[r * (NB + 1) + b + 1] - base;
    const unsigned int* pk = packed + (size_t)r * E + base;
    for (int i = t; i < BSZ; i += 256) pos[i] = 0;
    __syncthreads();
    for (int i = t; i < cnt; i += 256) atomicAdd(&pos[pk[i] >> 17], 1);
    __syncthreads();
    int v[4];
    int s = 0;
#pragma unroll
    for (int i = 0; i < 4; i++) {
        v[i] = pos[t * 4 + i];
        s += v[i];
    }
    tsum[t] = s;
    __syncthreads();
    for (int off = 1; off < 256; off <<= 1) {
        int add = (t >= off) ? tsum[t - off] : 0;
        __syncthreads();
        tsum[t] += add;
        __syncthreads();
    }
    int run = tsum[t] - s;  // exclusive
    __syncthreads();
#pragma unroll
    for (int i = 0; i < 4; i++) {
        int node_l = t * 4 + i;
        pos[node_l] = run;
        int node = b * BSZ + node_l;
        if (node < N) csr_ptr[(size_t)r * (N + 1) + node] = base + run;
        run += v[i];
    }
    __syncthreads();
    for (int i = t; i < cnt; i += 256) {
        unsigned int p = pk[i];
        int d = p >> 17;
        int sidx = p & 0x1FFFF;
        int loc = atomicAdd(&pos[d], 1);
        csr_src[(size_t)r * E + base + loc] = sidx;
    }
}

// ---------- edge-parallel logit gather: e_edge[j] = as_[csr_src[j]] ----------
// Chain-free, massive MLP; as_ (400KB/relation) is L2-resident.
__global__ __launch_bounds__(256) void k_elog(const int* __restrict__ csr_src,
                                              const float* __restrict__ as4,
                                              float* __restrict__ e_edge, int E, int N) {
    int r = blockIdx.y;
    const int* cs = csr_src + (size_t)r * E;
    const float* as_ = as4 + (size_t)r * N;
    float* ee = e_edge + (size_t)r * E;
    int base = blockIdx.x * 1024 + threadIdx.x;
    int s[4];
#pragma unroll
    for (int u = 0; u < 4; u++) {
        int e = base + u * 256;
        s[u] = (e < E) ? cs[e] : 0;
    }
#pragma unroll
    for (int u = 0; u < 4; u++) {
        int e = base + u * 256;
        if (e < E) ee[e] = as_[s[u]];
    }
}

// ======== MFMA GEMM kernels: M-tile 256 (4 waves x 64 rows), N=64, 16x16x32 bf16 ========

// ---------- fused h-gemm: h_r = X@Wg_r (bf16, pi-packed), as/ad = X@wvec ----------
__global__ __launch_bounds__(256, 3) void k_hgemm(const unsigned short* __restrict__ X,
                                                  const unsigned short* __restrict__ WgTl,
                                                  const float* __restrict__ wsrcl,
                                                  const float* __restrict__ wdstl,
                                                  unsigned short* __restrict__ h4,
                                                  float* __restrict__ as4,
                                                  float* __restrict__ ad4, int N) {
    __shared__ __align__(16) unsigned short Xb[256][72];
    __shared__ __align__(16) unsigned short Wb[64][72];
    __shared__ float wsS[4][64], wdS[4][64];
    int tid = threadIdx.x, wave = tid >> 6, lane = tid & 63;
    int l15 = lane & 15, q = lane >> 4;
    int row0 = blockIdx.x * 256;
#pragma unroll
    for (int i = 0; i < 8; i++) {
        int f = tid + 256 * i;
        int rr = f >> 3, seg = f & 7;
        int grow = row0 + rr;
        short8 v = (short8){0, 0, 0, 0, 0, 0, 0, 0};
        if (grow < N) v = *(const short8*)(X + (size_t)grow * 320 + seg * 8);
        *(short8*)&Xb[rr][seg * 8] = v;
    }
    wsS[tid >> 6][tid & 63] = wsrcl[tid];
    wdS[tid >> 6][tid & 63] = wdstl[tid];
    __syncthreads();
    short8 afr[4][2];
#pragma unroll
    for (int mt = 0; mt < 4; mt++)
#pragma unroll
        for (int ks = 0; ks < 2; ks++)
            afr[mt][ks] = *(const short8*)&Xb[wave * 64 + mt * 16 + l15][ks * 32 + q * 8];
    {
        int grow = row0 + tid;
        float s[4] = {0.f, 0.f, 0.f, 0.f}, d[4] = {0.f, 0.f, 0.f, 0.f};
#pragma unroll
        for (int seg = 0; seg < 8; seg++) {
            short8 v = *(const short8*)&Xb[tid][seg * 8];
#pragma unroll
            for (int j = 0; j < 8; j++) {
                float xv = bf2f((unsigned short)v[j]);
                int k = seg * 8 + j;
#pragma unroll
                for (int r = 0; r < 4; r++) {
                    s[r] += xv * wsS[r][k];
                    d[r] += xv * wdS[r][k];
                }
            }
        }
        if (grow < N) {
#pragma unroll
            for (int r = 0; r < 4; r++) {
                as4[(size_t)r * N + grow] = s[r];
                ad4[(size_t)r * N + grow] = d[r];
            }
        }
    }
    for (int r = 0; r < 4; r++) {
        __syncthreads();
#pragma unroll
        for (int i = 0; i < 2; i++) {
            int f = tid + 256 * i;
            int n = f >> 3, seg = f & 7;
            *(short8*)&Wb[n][seg * 8] = *(const short8*)(WgTl + r * 4096 + n * 64 + seg * 8);
        }
        __syncthreads();
        short8 bfr[4][2];
#pragma unroll
        for (int nt = 0; nt < 4; nt++)
#pragma unroll
            for (int ks = 0; ks < 2; ks++)
                bfr[nt][ks] = *(const short8*)&Wb[nt * 16 + l15][ks * 32 + q * 8];
        float4v acc[4][4];
#pragma unroll
        for (int mt = 0; mt < 4; mt++)
#pragma unroll
            for (int nt = 0; nt < 4; nt++) acc[mt][nt] = (float4v){0.f, 0.f, 0.f, 0.f};
#pragma unroll
        for (int mt = 0; mt < 4; mt++)
#pragma unroll
            for (int nt = 0; nt < 4; nt++) {
                acc[mt][nt] = __builtin_amdgcn_mfma_f32_16x16x32_bf16(afr[mt][0], bfr[nt][0],
                                                                     acc[mt][nt], 0, 0, 0);
                acc[mt][nt] = __builtin_amdgcn_mfma_f32_16x16x32_bf16(afr[mt][1], bfr[nt][1],
                                                                     acc[mt][nt], 0, 0, 0);
            }
        unsigned short* hr = h4 + (size_t)r * N * 64;
#pragma unroll
        for (int mt = 0; mt < 4; mt++) {
            int rowb = row0 + wave * 64 + mt * 16 + q * 4;
#pragma unroll
            for (int reg = 0; reg < 4; reg++) {
                int row = rowb + reg;
                if (row < N) {
                    short4v sv;
                    sv[0] = (short)f2bf(acc[mt][0][reg]);
                    sv[1] = (short)f2bf(acc[mt][1][reg]);
                    sv[2] = (short)f2bf(acc[mt][2][reg]);
                    sv[3] = (short)f2bf(acc[mt][3][reg]);
                    *(short4v*)&hr[(size_t)row * 64 + l15 * 4] = sv;
                }
            }
        }
    }
}

// ---------- W1 gemm: hid = tanh(combined[N,320](bf16) @ W1 + b1), bf16 out ----------
__global__ __launch_bounds__(256, 3) void k_w1gemm(const unsigned short* __restrict__ X,
                                                   const unsigned short* __restrict__ WT,
                                                   const float* __restrict__ bias,
                                                   unsigned short* __restrict__ Y, int N) {
    __shared__ __align__(16) unsigned short Xb[256][72];
    __shared__ __align__(16) unsigned short Wb[64][72];
    int tid = threadIdx.x, wave = tid >> 6, lane = tid & 63;
    int l15 = lane & 15, q = lane >> 4;
    int row0 = blockIdx.x * 256;
    float4v acc[4][4];
#pragma unroll
    for (int mt = 0; mt < 4; mt++)
#pragma unroll
        for (int nt = 0; nt < 4; nt++) acc[mt][nt] = (float4v){0.f, 0.f, 0.f, 0.f};
    for (int kc = 0; kc < 320; kc += 64) {
        __syncthreads();
#pragma unroll
        for (int i = 0; i < 8; i++) {
            int f = tid + 256 * i;
            int rr = f >> 3, seg = f & 7;
            int grow = row0 + rr;
            short8 v = (short8){0, 0, 0, 0, 0, 0, 0, 0};
            if (grow < N) v = *(const short8*)(X + (size_t)grow * 320 + kc + seg * 8);
            *(short8*)&Xb[rr][seg * 8] = v;
        }
#pragma unroll
        for (int i = 0; i < 2; i++) {
            int f = tid + 256 * i;
            int n = f >> 3, seg = f & 7;
            *(short8*)&Wb[n][seg * 8] = *(const short8*)(WT + n * 320 + kc + seg * 8);
        }
        __syncthreads();
        short8 bfr[4][2];
#pragma unroll
        for (int nt = 0; nt < 4; nt++)
#pragma unroll
            for (int ks = 0; ks < 2; ks++)
                bfr[nt][ks] = *(const short8*)&Wb[nt * 16 + l15][ks * 32 + q * 8];
#pragma unroll
        for (int mt = 0; mt < 4; mt++) {
            short8 a0 = *(const short8*)&Xb[wave * 64 + mt * 16 + l15][q * 8];
            short8 a1 = *(const short8*)&Xb[wave * 64 + mt * 16 + l15][32 + q * 8];
#pragma unroll
            for (int nt = 0; nt < 4; nt++) {
                acc[mt][nt] =
                    __builtin_amdgcn_mfma_f32_16x16x32_bf16(a0, bfr[nt][0], acc[mt][nt], 0, 0, 0);
                acc[mt][nt] =
                    __builtin_amdgcn_mfma_f32_16x16x32_bf16(a1, bfr[nt][1], acc[mt][nt], 0, 0, 0);
            }
        }
    }
#pragma unroll
    for (int mt = 0; mt < 4; mt++) {
        int rowb = row0 + wave * 64 + mt * 16 + q * 4;
#pragma unroll
        for (int reg = 0; reg < 4; reg++) {
            int row = rowb + reg;
            if (row < N) {
#pragma unroll
                for (int nt = 0; nt < 4; nt++) {
                    int n = nt * 16 + l15;
                    float v = tanhf(acc[mt][nt][reg] + bias[n]);
                    Y[(size_t)row * 64 + n] = f2bf(v);
                }
            }
        }
    }
}

// ---------- W2 gemm: dest = hid[N,64](bf16) @ W2 + b2; bf16 (layer0) or fp32 out ----------
template <bool BFOUT>
__global__ __launch_bounds__(256, 3) void k_w2gemm(const unsigned short* __restrict__ X,
                                                   const unsigned short* __restrict__ WT,
                                                   const float* __restrict__ bias,
                                                   unsigned short* __restrict__ Ybf,
                                                   float* __restrict__ Yf, int ldy, int N) {
    __shared__ __align__(16) unsigned short Xb[256][72];
    __shared__ __align__(16) unsigned short Wb[64][72];
    int tid = threadIdx.x, wave = tid >> 6, lane = tid & 63;
    int l15 = lane & 15, q = lane >> 4;
    int row0 = blockIdx.x * 256;
#pragma unroll
    for (int i = 0; i < 8; i++) {
        int f = tid + 256 * i;
        int rr = f >> 3, seg = f & 7;
        int grow = row0 + rr;
        short8 v = (short8){0, 0, 0, 0, 0, 0, 0, 0};
        if (grow < N) v = *(const short8*)(X + (size_t)grow * 64 + seg * 8);
        *(short8*)&Xb[rr][seg * 8] = v;
    }
#pragma unroll
    for (int i = 0; i < 2; i++) {
        int f = tid + 256 * i;
        int n = f >> 3, seg = f & 7;
        *(short8*)&Wb[n][seg * 8] = *(const short8*)(WT + n * 64 + seg * 8);
    }
    __syncthreads();
    short8 bfr[4][2];
#pragma unroll
    for (int nt = 0; nt < 4; nt++)
#pragma unroll
        for (int ks = 0; ks < 2; ks++)
            bfr[nt][ks] = *(const short8*)&Wb[nt * 16 + l15][ks * 32 + q * 8];
    float4v acc[4][4];
#pragma unroll
    for (int mt = 0; mt < 4; mt++)
#pragma unroll
        for (int nt = 0; nt < 4; nt++) acc[mt][nt] = (float4v){0.f, 0.f, 0.f, 0.f};
#pragma unroll
    for (int mt = 0; mt < 4; mt++) {
        short8 a0 = *(const short8*)&Xb[wave * 64 + mt * 16 + l15][q * 8];
        short8 a1 = *(const short8*)&Xb[wave * 64 + mt * 16 + l15][32 + q * 8];
#pragma unroll
        for (int nt = 0; nt < 4; nt++) {
            acc[mt][nt] =
                __builtin_amdgcn_mfma_f32_16x16x32_bf16(a0, bfr[nt][0], acc[mt][nt], 0, 0, 0);
            acc[mt][nt] =
                __builtin_amdgcn_mfma_f32_16x16x32_bf16(a1, bfr[nt][1], acc[mt][nt], 0, 0, 0);
        }
    }
#pragma unroll
    for (int mt = 0; mt < 4; mt++) {
        int rowb = row0 + wave * 64 + mt * 16 + q * 4;
#pragma unroll
        for (int reg = 0; reg < 4; reg++) {
            int row = rowb + reg;
            if (row < N) {
#pragma unroll
                for (int nt = 0; nt < 4; nt++) {
                    int n = nt * 16 + l15;
                    float v = acc[mt][nt][reg] + bias[n];
                    if (BFOUT)
                        Ybf[(size_t)row * ldy + n] = f2bf(v);
                    else
                        Yf[(size_t)row * ldy + n] = v;
                }
            }
        }
    }
}

// ---------- full-wave per-node GAT (proven path; rare fallback, bf16 out) ----------
__device__ void gat_node_fullwave(int node, const int* __restrict__ csr_ptr,
                                  const int* __restrict__ csr_src,
                                  const float* __restrict__ e_edge,
                                  const unsigned short* __restrict__ h,
                                  const float* __restrict__ as_,
                                  const float* __restrict__ ad_, float bgv,
                                  unsigned short* __restrict__ out, int ldo, int lane) {
    float adv = ad_[node];
    float e_self = lrelu(as_[node] + adv);
    int beg = csr_ptr[node], end = csr_ptr[node + 1];
    int cnt = end - beg;

    if (cnt <= 64) {
        int s = 0;
        float e_lane = -3.0e38f;
        if (lane < cnt) {
            s = csr_src[beg + lane];
            e_lane = lrelu(e_edge[beg + lane] + adv);
        }
        float m = fmaxf(e_lane, e_self);
#pragma unroll
        for (int off = 32; off; off >>= 1) m = fmaxf(m, __shfl_xor(m, off));
        float p = (lane < cnt) ? expf(e_lane - m) : 0.f;
        float ssum = p;
#pragma unroll
        for (int off = 32; off; off >>= 1) ssum += __shfl_xor(ssum, off);
        float p_self = expf(e_self - m);
        float inv = 1.f / (ssum + p_self);
        float alpha = p * inv;
        float acc = p_self * inv * bf2f(h[(size_t)node * DD + lane]);
        for (int j0 = 0; j0 < cnt; ++j0) {
            int ss = __shfl(s, j0);
            float aa = __shfl(alpha, j0);
            acc += aa * bf2f(h[(size_t)ss * DD + lane]);
        }
        out[(size_t)node * ldo + lane] = f2bf(acc + bgv);
        return;
    }

    float m = e_self;
    for (int j = beg + lane; j < end; j += 64) m = fmaxf(m, lrelu(e_edge[j] + adv));
#pragma unroll
    for (int off = 32; off; off >>= 1) m = fmaxf(m, __shfl_xor(m, off));
    float ssum = 0.f;
    for (int j = beg + lane; j < end; j += 64) ssum += expf(lrelu(e_edge[j] + adv) - m);
#pragma unroll
    for (int off = 32; off; off >>= 1) ssum += __shfl_xor(ssum, off);
    ssum += expf(e_self - m);
    float inv = 1.f / ssum;
    float acc = expf(e_self - m) * inv * bf2f(h[(size_t)node * DD + lane]);
    for (int j0 = beg; j0 < end; j0 += 64) {
        int j = j0 + lane;
        int s = 0;
        float alpha = 0.f;
        if (j < end) {
            s = csr_src[j];
            alpha = expf(lrelu(e_edge[j] + adv) - m) * inv;
        }
        int c = end - j0;
        if (c > 64) c = 64;
        for (int t = 0; t < c; ++t) {
            int ss = __shfl(s, t);
            float aa = __shfl(alpha, t);
            acc += aa * bf2f(h[(size_t)ss * DD + lane]);
        }
    }
    out[(size_t)node * ldo + lane] = f2bf(acc + bgv);
}

// ---------- GAT: merged over relations (blockIdx.y = r), two nodes per wave ----------
// e_edge precomputed (k_elog) -> softmax phase reads sequentially; csr_src only
// needed for aggregation (independent load). Cross-half transport:
// WAVE-UNIFORM-source __shfl + per-half cndmask only (R3/R4 divergent-index
// transport raced — do not reintroduce).
__global__ __launch_bounds__(256) void k_gat(const int* __restrict__ csr_ptr4,
                                             const int* __restrict__ csr_src4,
                                             const float* __restrict__ e_edge4,
                                             const unsigned short* __restrict__ h4,
                                             const float* __restrict__ as4,
                                             const float* __restrict__ ad4,
                                             const float* __restrict__ bg4,
                                             unsigned short* __restrict__ outbase, int ldo,
                                             int N, int E) {
    int r = blockIdx.y;
    const int* csr_ptr = csr_ptr4 + (size_t)r * (N + 1);
    const int* csr_src = csr_src4 + (size_t)r * E;
    const float* e_edge = e_edge4 + (size_t)r * E;
    const unsigned short* h = h4 + (size_t)r * N * 64;
    const float* as_ = as4 + (size_t)r * N;
    const float* ad_ = ad4 + (size_t)r * N;
    const float* bg = bg4 + (size_t)r * DD;
    unsigned short* out = outbase + (size_t)64 * r;

    int wave = threadIdx.x >> 6, lane = threadIdx.x & 63;
    int half = lane >> 5, lh = lane & 31;
    int nodeA = blockIdx.x * 8 + wave * 2;
    int node = nodeA + half;
    bool active = node < N;
    int beg = 0, cnt = 0;
    if (active) {
        beg = csr_ptr[node];
        cnt = csr_ptr[node + 1] - beg;
    }
    int ocnt = __shfl_xor(cnt, 32);
    int vmax = max(cnt, ocnt);  // wave-uniform

    if (vmax <= 32) {
        float adv = active ? ad_[node] : 0.f;
        float e_self = active ? lrelu(as_[node] + adv) : -3.0e38f;
        int s = 0;
        float ev = 0.f;
        if (lh < cnt) {
            s = csr_src[beg + lh];   // independent sequential load
            ev = e_edge[beg + lh];   // sequential load
        }
        float e_lane = (lh < cnt) ? lrelu(ev + adv) : -3.0e38f;
        float m = fmaxf(e_lane, e_self);
#pragma unroll
        for (int off = 16; off; off >>= 1) m = fmaxf(m, __shfl_xor(m, off));
        float p = (lh < cnt) ? expf(e_lane - m) : 0.f;
        float ssum = p;
#pragma unroll
        for (int off = 16; off; off >>= 1) ssum += __shfl_xor(ssum, off);
        float p_self = expf(e_self - m);
        float inv = 1.f / (ssum + p_self);
        float alpha = p * inv;

        float accx = 0.f, accy = 0.f;
        if (active) {
            unsigned int h2 = *(const unsigned int*)(h + (size_t)node * DD + lh * 2);
            float a_self = p_self * inv;
            accx = a_self * __uint_as_float(h2 << 16);
            accy = a_self * __uint_as_float(h2 & 0xffff0000u);
        }
        for (int j0 = 0; j0 < vmax; j0 += 8) {
#pragma unroll
            for (int u = 0; u < 8; u++) {
                int j = j0 + u;
                int sa = __shfl(s, j);  // uniform source lanes
                int sb = __shfl(s, j + 32);
                float aa = __shfl(alpha, j);
                float ab = __shfl(alpha, j + 32);
                int ss = half ? sb : sa;
                float av = half ? ab : aa;
                if (j < cnt) {
                    unsigned int h2 = *(const unsigned int*)(h + (size_t)ss * DD + lh * 2);
                    accx += av * __uint_as_float(h2 << 16);
                    accy += av * __uint_as_float(h2 & 0xffff0000u);
                }
            }
        }
        if (active) {
            int f0 = 2 * lh;
            float bx = bg[((f0 & 3) << 4) | (f0 >> 2)];        // pi^-1(2lh)
            float by = bg[(((f0 + 1) & 3) << 4) | (f0 >> 2)];  // pi^-1(2lh+1)
            unsigned int pck =
                (unsigned int)f2bf(accx + bx) | ((unsigned int)f2bf(accy + by) << 16);
            *(unsigned int*)(out + (size_t)node * ldo + f0) = pck;
        }
        return;
    }

    // rare fallback: whole wave handles each node sequentially (proven path)
    float bgv = bg[((lane & 3) << 4) | (lane >> 2)];
    if (nodeA < N)
        gat_node_fullwave(nodeA, csr_ptr, csr_src, e_edge, h, as_, ad_, bgv, out, ldo, lane);
    if (nodeA + 1 < N)
        gat_node_fullwave(nodeA + 1, csr_ptr, csr_src, e_edge, h, as_, ad_, bgv, out, ldo, lane);
}

extern "C" void kernel_launch(void* const* d_in, const int* in_sizes, int n_in,
                              void* d_out, int out_size, void* d_ws, size_t ws_size,
                              hipStream_t stream) {
    const float* x = (const float*)d_in[0];
    const int* edges = (const int*)d_in[1];
    const float* Wg = (const float*)d_in[2];
    const float* a_src = (const float*)d_in[3];
    const float* a_dst = (const float*)d_in[4];
    const float* bg = (const float*)d_in[5];
    const float* W1 = (const float*)d_in[6];
    const float* b1 = (const float*)d_in[7];
    const float* W2 = (const float*)d_in[8];
    const float* b2 = (const float*)d_in[9];
    float* out = (float*)d_out;

    const int N = in_sizes[0] / DD;          // 100000
    const int E = in_sizes[1] / (2 * RREL);  // 1000000
    const int NB = (N + BSZ - 1) >> BSH;     // 98 buckets (requires N <= 131072)

    // workspace layout (256B aligned)
    size_t off = 0;
    auto alloc = [&](size_t bytes) {
        size_t o = off;
        off = (off + bytes + 255) & ~(size_t)255;
        return o;
    };
    char* ws = (char*)d_ws;
    unsigned short* combined = (unsigned short*)(ws + alloc((size_t)N * 320 * 2));  // bf16
    unsigned short* h4 = (unsigned short*)(ws + alloc((size_t)4 * N * 64 * 2));     // also hid
    float* wsrc = (float*)(ws + alloc(LLAY * RREL * DD * 4));
    float* wdst = (float*)(ws + alloc(LLAY * RREL * DD * 4));
    unsigned short* WgT = (unsigned short*)(ws + alloc(8 * 4096 * 2));
    unsigned short* W1T = (unsigned short*)(ws + alloc(2 * 64 * 320 * 2));
    unsigned short* W2T = (unsigned short*)(ws + alloc(2 * 4096 * 2));
    int* btot = (int*)(ws + alloc((size_t)RREL * NB * 4));
    int* bucketoff = (int*)(ws + alloc((size_t)RREL * (NB + 1) * 4));
    int* bpos = (int*)(ws + alloc((size_t)RREL * NB * 4));
    unsigned int* packed = (unsigned int*)(ws + alloc((size_t)RREL * E * 4));  // also as4/ad4
    int* csr_ptr = (int*)(ws + alloc((size_t)RREL * (N + 1) * 4));
    int* csr_src = (int*)(ws + alloc((size_t)RREL * E * 4));
    float* e_edge = (float*)(ws + alloc((size_t)RREL * E * 4));
    (void)ws_size;
    unsigned short* hid = h4;     // h4 dead when hid is produced
    float* as4 = (float*)packed;  // packed dead after CSR build
    float* ad4 = as4 + (size_t)4 * N;

    const int ebblocks = (E + EPB - 1) / EPB;

    // --- preprocessing ---
    k_zero<<<dim3((RREL * NB + 255) / 256), dim3(256), 0, stream>>>(btot, RREL * NB);
    k_wvec<<<dim3(2), dim3(256), 0, stream>>>(Wg, a_src, a_dst, wsrc, wdst);
    k_prep<<<dim3(320), dim3(256), 0, stream>>>(Wg, W1, W2, WgT, W1T, W2T);
    k_copy_x<<<dim3((N * 32 + 255) / 256), dim3(256), 0, stream>>>(x, combined, N);
    k_bhist<<<dim3(ebblocks, RREL), dim3(256), 0, stream>>>(edges, btot, E, NB);
    k_bscan<<<dim3(1), dim3(64), 0, stream>>>(btot, bucketoff, bpos, csr_ptr, N, E, NB);
    k_binscatter<<<dim3(ebblocks, RREL), dim3(256), 0, stream>>>(edges, bpos, packed, E, NB);
    k_bucket_sort<<<dim3(NB, RREL), dim3(256), 0, stream>>>(packed, bucketoff, csr_ptr, csr_src,
                                                            N, E, NB);

    const int gemm_blocks = (N + 255) / 256;
    const int gat_blocks = (N + 7) / 8;
    const int elog_blocks = (E + 1023) / 1024;

    for (int l = 0; l < LLAY; l++) {
        k_hgemm<<<dim3(gemm_blocks), dim3(256), 0, stream>>>(
            combined, WgT + (size_t)l * 4 * 4096, wsrc + l * 256, wdst + l * 256, h4, as4, ad4, N);
        k_elog<<<dim3(elog_blocks, RREL), dim3(256), 0, stream>>>(csr_src, as4, e_edge, E, N);
        k_gat<<<dim3(gat_blocks, RREL), dim3(256), 0, stream>>>(
            csr_ptr, csr_src, e_edge, h4, as4, ad4, bg + (size_t)l * RREL * DD,
            combined + 64, 320, N, E);
        k_w1gemm<<<dim3(gemm_blocks), dim3(256), 0, stream>>>(combined, W1T + (size_t)l * 20480,
                                                              b1 + l * DD, hid, N);
        if (l == LLAY - 1) {
            k_w2gemm<false><<<dim3(gemm_blocks), dim3(256), 0, stream>>>(
                hid, W2T + (size_t)l * 4096, b2 + l * DD, nullptr, out, DD, N);
        } else {
            k_w2gemm<true><<<dim3(gemm_blocks), dim3(256), 0, stream>>>(
                hid, W2T + (size_t)l * 4096, b2 + l * DD, combined, nullptr, 320, N);
        }
    }
}